// Round 9
// baseline (172.780 us; speedup 1.0000x reference)
//
#include <hip/hip_runtime.h>
#include <stdint.h>

// ---------------- JAX threefry2x32 (partitionable mode) ----------------
__host__ __device__ inline void tf2x32(uint32_t k0, uint32_t k1,
                                       uint32_t x0, uint32_t x1,
                                       uint32_t& o0, uint32_t& o1) {
  const uint32_t ks2 = k0 ^ k1 ^ 0x1BD11BDAu;
  x0 += k0; x1 += k1;
#define TFR(r) { x0 += x1; x1 = (x1 << (r)) | (x1 >> (32 - (r))); x1 ^= x0; }
  TFR(13) TFR(15) TFR(26) TFR(6)
  x0 += k1;  x1 += ks2 + 1u;
  TFR(17) TFR(29) TFR(16) TFR(24)
  x0 += ks2; x1 += k0 + 2u;
  TFR(13) TFR(15) TFR(26) TFR(6)
  x0 += k0;  x1 += k1 + 3u;
  TFR(17) TFR(29) TFR(16) TFR(24)
  x0 += k1;  x1 += ks2 + 4u;
  TFR(13) TFR(15) TFR(26) TFR(6)
  x0 += ks2; x1 += k0 + 5u;
#undef TFR
  o0 = x0; o1 = x1;
}

__host__ __device__ inline uint32_t bits32(uint32_t k0, uint32_t k1, uint32_t idx) {
  uint32_t a, b;
  tf2x32(k0, k1, 0u, idx, a, b);
  return a ^ b;
}

// keep-edge iff uniform >= 0.5 iff bit31 of bits set (floor(0.5+u) == 1)
__device__ inline bool edge_kept(uint32_t k0, uint32_t k1, uint32_t e) {
  return (bits32(k0, k1, e) >> 31) != 0u;
}

__device__ inline float bf_lo(uint32_t u) { return __uint_as_float(u << 16); }
__device__ inline float bf_hi(uint32_t u) { return __uint_as_float(u & 0xffff0000u); }
__device__ inline uint32_t bf_pack(float a, float b) {
  uint32_t lo = (__float_as_uint(a) + 0x8000u) >> 16;
  uint32_t hi = (__float_as_uint(b) + 0x8000u) & 0xffff0000u;
  return hi | lo;
}

// lane j owns dims {4j..4j+3} u {32+4j..32+4j+3}; a[0..3] first group, a[4..7] second
__device__ inline void fma8_f32(float a[8], float v, const float4& x0, const float4& x1) {
  a[0] = fmaf(v, x0.x, a[0]); a[1] = fmaf(v, x0.y, a[1]);
  a[2] = fmaf(v, x0.z, a[2]); a[3] = fmaf(v, x0.w, a[3]);
  a[4] = fmaf(v, x1.x, a[4]); a[5] = fmaf(v, x1.y, a[5]);
  a[6] = fmaf(v, x1.z, a[6]); a[7] = fmaf(v, x1.w, a[7]);
}
__device__ inline void fma8_bf(float a[8], float v, const uint4& u) {
  a[0] = fmaf(v, bf_lo(u.x), a[0]); a[1] = fmaf(v, bf_hi(u.x), a[1]);
  a[2] = fmaf(v, bf_lo(u.y), a[2]); a[3] = fmaf(v, bf_hi(u.y), a[3]);
  a[4] = fmaf(v, bf_lo(u.z), a[4]); a[5] = fmaf(v, bf_hi(u.z), a[5]);
  a[6] = fmaf(v, bf_lo(u.w), a[6]); a[7] = fmaf(v, bf_hi(u.w), a[7]);
}

#define SMALLMAX 4

// ---------------- keep bits + first-half block sums + item counts +
//                  batch marking, one pass ----------------
__global__ __launch_bounds__(1024) void k_keep(
    const int* __restrict__ rows, int E, int E2, int nu,
    unsigned long long* __restrict__ keepw, int* __restrict__ bsumE,
    int* __restrict__ cnt, const int* __restrict__ users,
    const int* __restrict__ items, int batch,
    uint8_t* fB, uint8_t* f1, uint8_t* f2, uint32_t ke0, uint32_t ke1) {
  __shared__ int s[16];
  int e = blockIdx.x * 1024 + threadIdx.x;
  int lane = threadIdx.x & 63;
  int wid = threadIdx.x >> 6;
  bool kept = (e < E) && edge_kept(ke0, ke1, (uint32_t)e);
  unsigned long long m = __ballot(kept);
  int ws = blockIdx.x * 1024 + wid * 64;
  if (lane == 0 && ws < E) keepw[ws >> 6] = m;
  int nf = 0;
  if (ws + 64 <= E2) nf = __popcll(m);
  else if (ws < E2) nf = __popcll(m & ((1ull << (E2 - ws)) - 1ull));
  if (lane == 0) s[wid] = nf;
  __syncthreads();
  if (threadIdx.x == 0) {
    int t = 0;
    for (int i = 0; i < 16; ++i) t += s[i];
    bsumE[blockIdx.x] = t;
  }
  if (kept && e >= E2) atomicAdd(&cnt[rows[e] - nu], 1);
  // batch marking (covered by first blocks)
  if (e < 2 * batch) {
    int r = (e < batch) ? users[e] : nu + items[e - batch];
    fB[r] = 1; f1[r] = 1; f2[r] = 1;
  }
}

// single block, 1024 threads, scans up to 2048 block sums -> exclusive prefix
__device__ inline void scan_block_1024(const int* __restrict__ bsum, int nb,
                                       int* __restrict__ bpref,
                                       int* a, int* b) {
  int t = threadIdx.x;
  for (int i = t; i < 2048; i += 1024) a[i] = (i < nb) ? bsum[i] : 0;
  __syncthreads();
  int* cur = a; int* nxt = b;
  for (int off = 1; off < 2048; off <<= 1) {
    for (int i = t; i < 2048; i += 1024)
      nxt[i] = cur[i] + (i >= off ? cur[i - off] : 0);
    __syncthreads();
    int* tmp = cur; cur = nxt; nxt = tmp;
  }
  for (int i = t; i <= nb; i += 1024)
    bpref[i] = (i == 0) ? 0 : cur[i - 1];
  __syncthreads();
}

__global__ void k_scanb2x(const int* __restrict__ bA, int nA, int* __restrict__ pA,
                          const int* __restrict__ bB, int nB, int* __restrict__ pB) {
  __shared__ int a[2048], b[2048];
  scan_block_1024(bA, nA, pA, a, b);
  scan_block_1024(bB, nB, pB, a, b);
}

__global__ void k_scanb4(const int* __restrict__ b1, int* __restrict__ p1,
                         const int* __restrict__ b2, int* __restrict__ p2,
                         const int* __restrict__ b3, int* __restrict__ p3,
                         const int* __restrict__ b4, int* __restrict__ p4, int nb) {
  __shared__ int a[2048], b[2048];
  scan_block_1024(b1, nb, p1, a, b);
  scan_block_1024(b2, nb, p2, a, b);
  scan_block_1024(b3, nb, p3, a, b);
  scan_block_1024(b4, nb, p4, a, b);
}

__global__ void k_blocksum(const int* __restrict__ cnt, int n, int* __restrict__ bsum) {
  __shared__ int s[256];
  int i = blockIdx.x * 256 + threadIdx.x;
  s[threadIdx.x] = (i < n) ? cnt[i] : 0;
  __syncthreads();
  for (int off = 128; off > 0; off >>= 1) {
    if (threadIdx.x < off) s[threadIdx.x] += s[threadIdx.x + off];
    __syncthreads();
  }
  if (threadIdx.x == 0) bsum[blockIdx.x] = s[0];
}

// writes unified row_ptr[NU..NN] and nextc, both offset by keptU (*basep)
__global__ void k_scan_write(const int* __restrict__ cnt, int n, const int* __restrict__ bpref,
                             const int* __restrict__ basep,
                             int* __restrict__ row_ptr_i, int* __restrict__ nextc) {
  __shared__ int a[256], b[256];
  int t = threadIdx.x;
  int i = blockIdx.x * 256 + t;
  int v = (i < n) ? cnt[i] : 0;
  a[t] = v;
  __syncthreads();
  int* cur = a; int* nxt = b;
  for (int off = 1; off < 256; off <<= 1) {
    nxt[t] = cur[t] + (t >= off ? cur[t - off] : 0);
    __syncthreads();
    int* tmp = cur; cur = nxt; nxt = tmp;
  }
  int base = *basep;
  int incl = cur[t] + bpref[blockIdx.x] + base;
  int excl = incl - v;
  if (i < n) { row_ptr_i[i] = excl; nextc[i] = excl; }
  if (i == n - 1) row_ptr_i[n] = incl;
}

// ---- user-half compaction: coalesced writes into unified slot[0..keptU),
//      row_ptr[0..NU] from boundaries of sorted rows. Deterministic. ----
__global__ __launch_bounds__(1024) void k_compactU(
    const int* __restrict__ rows, const int* __restrict__ cols,
    const float* __restrict__ avals, const unsigned long long* __restrict__ keepw,
    const int* __restrict__ bprefE, int E2, int nu, int nbE,
    int2* __restrict__ slot, int* __restrict__ row_ptr) {
  __shared__ int a[1024], b[1024];
  int t = threadIdx.x;
  int e = blockIdx.x * 1024 + t;
  bool kept = (e < E2) && ((keepw[e >> 6] >> (e & 63)) & 1ull);
  a[t] = kept ? 1 : 0;
  __syncthreads();
  int* cur = a; int* nxt = b;
  for (int off = 1; off < 1024; off <<= 1) {
    nxt[t] = cur[t] + (t >= off ? cur[t - off] : 0);
    __syncthreads();
    int* tmp = cur; cur = nxt; nxt = tmp;
  }
  int excl = cur[t] - (kept ? 1 : 0);
  int pos = bprefE[blockIdx.x] + excl;
  if (kept) slot[pos] = make_int2(cols[e], __float_as_int(avals[e] * 2.0f));
  if (e < E2) {
    int r = rows[e];
    int rp = (e == 0) ? -1 : rows[e - 1];
    for (int rr = rp + 1; rr <= r; ++rr) row_ptr[rr] = pos;
    if (e == E2 - 1) {
      int total = bprefE[nbE];
      for (int rr = r + 1; rr <= nu; ++rr) row_ptr[rr] = total;
    }
  }
}

// ---- item-half scatter into slot[keptU..) (nextc pre-offset) ----
__global__ void k_scatterI(const int* __restrict__ rows, const int* __restrict__ cols,
                           const float* __restrict__ avals,
                           const unsigned long long* __restrict__ keepw,
                           int E, int E2, int nu, int* __restrict__ nextc,
                           int2* __restrict__ slot) {
  int e = E2 + blockIdx.x * 256 + threadIdx.x;
  if (e >= E) return;
  if (!((keepw[e >> 6] >> (e & 63)) & 1ull)) return;
  int r = rows[e] - nu;
  int k = atomicAdd(&nextc[r], 1);
  slot[k] = make_int2(cols[e], __float_as_int(avals[e] * 2.0f));
}

// ---------------- frontier marking (unified CSR) ----------------
__global__ void k_mark_neighbors(const uint8_t* __restrict__ fin,
                                 const int* __restrict__ row_ptr,
                                 const int2* __restrict__ slot, int n,
                                 uint8_t* __restrict__ fout) {
  int r = blockIdx.x * 256 + threadIdx.x;
  if (r >= n) return;
  if (!fin[r]) return;
  int s = row_ptr[r], e = row_ptr[r + 1];
  for (int k = s; k < e; ++k) fout[slot[k].x] = 1;
}

// per-block sums of 4 categories: f1-small, f1-big, f2-small, f2-big
__global__ void k_flagsum4(const uint8_t* __restrict__ f1, const uint8_t* __restrict__ f2,
                           const int* __restrict__ row_ptr, int n,
                           int* __restrict__ bs1, int* __restrict__ bb1,
                           int* __restrict__ bs2, int* __restrict__ bb2) {
  __shared__ int h0[256], h1[256], h2[256], h3[256];
  int t = threadIdx.x;
  int i = blockIdx.x * 256 + t;
  int deg = 0; bool a1 = false, a2 = false;
  if (i < n) {
    int s = row_ptr[i], e = row_ptr[i + 1];
    deg = e - s;
    a1 = f1[i]; a2 = f2[i];
  }
  bool sm = deg <= SMALLMAX;
  h0[t] = (a1 && sm) ? 1 : 0; h1[t] = (a1 && !sm) ? 1 : 0;
  h2[t] = (a2 && sm) ? 1 : 0; h3[t] = (a2 && !sm) ? 1 : 0;
  __syncthreads();
  for (int off = 128; off > 0; off >>= 1) {
    if (t < off) {
      h0[t] += h0[t + off]; h1[t] += h1[t + off];
      h2[t] += h2[t + off]; h3[t] += h3[t + off];
    }
    __syncthreads();
  }
  if (t == 0) {
    bs1[blockIdx.x] = h0[0]; bb1[blockIdx.x] = h1[0];
    bs2[blockIdx.x] = h2[0]; bb2[blockIdx.x] = h3[0];
  }
}

__device__ inline void emit_pass(bool flag, int r, int s, int e,
                                 const int* __restrict__ bpref, int base0,
                                 int4* __restrict__ list, int* a, int* b) {
  int t = threadIdx.x;
  a[t] = flag ? 1 : 0;
  __syncthreads();
  int* cur = a; int* nxt = b;
  for (int off = 1; off < 256; off <<= 1) {
    nxt[t] = cur[t] + (t >= off ? cur[t - off] : 0);
    __syncthreads();
    int* tmp = cur; cur = nxt; nxt = tmp;
  }
  if (flag) list[base0 + bpref[blockIdx.x] + cur[t] - 1] = make_int4(r, s, e, 0);
  __syncthreads();
}

// lists: [smalls | bigs] per frontier; entries (row, edge_start, edge_end)
__global__ void k_compact4(const uint8_t* __restrict__ f1, const uint8_t* __restrict__ f2,
                           const int* __restrict__ row_ptr, int n, int nb,
                           const int* __restrict__ ps1, const int* __restrict__ pb1,
                           const int* __restrict__ ps2, const int* __restrict__ pb2,
                           int4* __restrict__ list1, int4* __restrict__ list2) {
  __shared__ int a[256], b[256];
  int i = blockIdx.x * 256 + threadIdx.x;
  int s = 0, e = 0; bool a1 = false, a2 = false;
  if (i < n) {
    s = row_ptr[i]; e = row_ptr[i + 1];
    a1 = f1[i]; a2 = f2[i];
  }
  bool sm = (e - s) <= SMALLMAX;
  emit_pass(a1 && sm, i, s, e, ps1, 0, list1, a, b);
  emit_pass(a1 && !sm, i, s, e, pb1, ps1[nb], list1, a, b);
  emit_pass(a2 && sm, i, s, e, ps2, 0, list2, a, b);
  emit_pass(a2 && !sm, i, s, e, pb2, ps2[nb], list2, a, b);
}

// -------- SPMM: 8 lanes/row (lane j owns dims 4j..4j+3, 32+4j..32+4j+3),
//          int4 list entries (r,s,e), degree-homogeneous waves --------
template <int FIRST>
__global__ __launch_bounds__(256) void k_spmm(
    const int2* __restrict__ slot, const uint32_t* __restrict__ xin,
    const float* __restrict__ uemb, const float* __restrict__ iemb,
    uint32_t* __restrict__ xout, const int4* __restrict__ list,
    const int* __restrict__ nsp, const int* __restrict__ nbp, int nu) {
  int nrows = *nsp + *nbp;
  int i = blockIdx.x * 32 + (threadIdx.x >> 3);
  if (i >= nrows) return;
  int4 ent = list[i];
  int r = ent.x, s = ent.y, e = ent.z;
  int j = threadIdx.x & 7;
  float a[8] = {0, 0, 0, 0, 0, 0, 0, 0};
  int last = e - 1;
  for (int k = s; k < e; k += 4) {
    int i1 = (k + 1 <= last) ? k + 1 : last;
    int i2 = (k + 2 <= last) ? k + 2 : last;
    int i3 = (k + 3 <= last) ? k + 3 : last;
    int2 s0 = slot[k], s1 = slot[i1], s2 = slot[i2], s3 = slot[i3];
    float v0 = __int_as_float(s0.y);
    float v1 = (k + 1 <= last) ? __int_as_float(s1.y) : 0.0f;
    float v2 = (k + 2 <= last) ? __int_as_float(s2.y) : 0.0f;
    float v3 = (k + 3 <= last) ? __int_as_float(s3.y) : 0.0f;
    if (FIRST) {
      const float* p0 = (s0.x < nu) ? uemb + (size_t)s0.x * 64
                                    : iemb + (size_t)(s0.x - nu) * 64;
      const float* p1 = (s1.x < nu) ? uemb + (size_t)s1.x * 64
                                    : iemb + (size_t)(s1.x - nu) * 64;
      const float* p2 = (s2.x < nu) ? uemb + (size_t)s2.x * 64
                                    : iemb + (size_t)(s2.x - nu) * 64;
      const float* p3 = (s3.x < nu) ? uemb + (size_t)s3.x * 64
                                    : iemb + (size_t)(s3.x - nu) * 64;
      float4 xa0 = *(const float4*)(p0 + 4 * j);
      float4 xb0 = *(const float4*)(p0 + 32 + 4 * j);
      float4 xa1 = *(const float4*)(p1 + 4 * j);
      float4 xb1 = *(const float4*)(p1 + 32 + 4 * j);
      float4 xa2 = *(const float4*)(p2 + 4 * j);
      float4 xb2 = *(const float4*)(p2 + 32 + 4 * j);
      float4 xa3 = *(const float4*)(p3 + 4 * j);
      float4 xb3 = *(const float4*)(p3 + 32 + 4 * j);
      fma8_f32(a, v0, xa0, xb0);
      fma8_f32(a, v1, xa1, xb1);
      fma8_f32(a, v2, xa2, xb2);
      fma8_f32(a, v3, xa3, xb3);
    } else {
      uint4 u0 = *(const uint4*)(xin + (size_t)s0.x * 32 + 4 * j);
      uint4 u1 = *(const uint4*)(xin + (size_t)s1.x * 32 + 4 * j);
      uint4 u2 = *(const uint4*)(xin + (size_t)s2.x * 32 + 4 * j);
      uint4 u3 = *(const uint4*)(xin + (size_t)s3.x * 32 + 4 * j);
      fma8_bf(a, v0, u0);
      fma8_bf(a, v1, u1);
      fma8_bf(a, v2, u2);
      fma8_bf(a, v3, u3);
    }
  }
  uint4 o;
  o.x = bf_pack(a[0], a[1]); o.y = bf_pack(a[2], a[3]);
  o.z = bf_pack(a[4], a[5]); o.w = bf_pack(a[6], a[7]);
  *(uint4*)(xout + (size_t)r * 32 + 4 * j) = o;
}

// ---- epilogue A (after layer 1): out_online = emb[row] + bf(X0[row]) ----
// out layout: [u_online | u_target | i_online | i_target], H = B*64 each.
__global__ void k_gatherA(const uint32_t* __restrict__ x0, const float* __restrict__ uemb,
                          const float* __restrict__ iemb, const int* __restrict__ users,
                          const int* __restrict__ items, float* __restrict__ out,
                          int batch, int nu) {
  int b = blockIdx.x * 32 + (threadIdx.x >> 3);
  if (b >= 2 * batch) return;
  int j = threadIdx.x & 7;
  size_t H = (size_t)batch * 64;
  int row; size_t dst; bool isu = b < batch;
  if (isu) {
    row = users[b];
    dst = (size_t)b * 64;
  } else {
    int bi = b - batch;
    row = items[bi];
    dst = 2 * H + (size_t)bi * 64;
  }
  const float* p = isu ? uemb + (size_t)row * 64 : iemb + (size_t)row * 64;
  float4 t0 = *(const float4*)(p + 4 * j);
  float4 t1 = *(const float4*)(p + 32 + 4 * j);
  int xr = isu ? row : nu + row;
  uint4 u = *(const uint4*)(x0 + (size_t)xr * 32 + 4 * j);
  t0.x += bf_lo(u.x); t0.y += bf_hi(u.x); t0.z += bf_lo(u.y); t0.w += bf_hi(u.y);
  t1.x += bf_lo(u.z); t1.y += bf_hi(u.z); t1.z += bf_lo(u.w); t1.w += bf_hi(u.w);
  *(float4*)(out + dst + 4 * j) = t0;
  *(float4*)(out + dst + 32 + 4 * j) = t1;
}

// ---- epilogue tail: += bf(X1[row]) [L2] + SPMM(X1)[row] [L3], /4, masks ----
__global__ __launch_bounds__(256) void k_tail(
    const int* __restrict__ row_ptr, const int2* __restrict__ slot,
    const uint32_t* __restrict__ x1, const int* __restrict__ users,
    const int* __restrict__ items, float* __restrict__ out,
    int batch, int nu,
    uint32_t ku0, uint32_t ku1, uint32_t ki0, uint32_t ki1) {
  int b = blockIdx.x * 32 + (threadIdx.x >> 3);
  if (b >= 2 * batch) return;
  int j = threadIdx.x & 7;
  size_t H = (size_t)batch * 64;
  int rr; size_t dst; int fbase; uint32_t mk0, mk1;
  bool isu = b < batch;
  if (isu) {
    rr = users[b];
    dst = (size_t)b * 64;
    fbase = b * 64;
    mk0 = ku0; mk1 = ku1;
  } else {
    int bi = b - batch;
    rr = nu + items[bi];
    dst = 2 * H + (size_t)bi * 64;
    fbase = (b - batch) * 64;
    mk0 = ki0; mk1 = ki1;
  }
  int s = row_ptr[rr], e = row_ptr[rr + 1];
  float a[8] = {0, 0, 0, 0, 0, 0, 0, 0};
  int last = e - 1;
  for (int k = s; k < e; k += 4) {
    int i1 = (k + 1 <= last) ? k + 1 : last;
    int i2 = (k + 2 <= last) ? k + 2 : last;
    int i3 = (k + 3 <= last) ? k + 3 : last;
    int2 s0 = slot[k], s1 = slot[i1], s2 = slot[i2], s3 = slot[i3];
    float v0 = __int_as_float(s0.y);
    float v1 = (k + 1 <= last) ? __int_as_float(s1.y) : 0.0f;
    float v2 = (k + 2 <= last) ? __int_as_float(s2.y) : 0.0f;
    float v3 = (k + 3 <= last) ? __int_as_float(s3.y) : 0.0f;
    uint4 u0 = *(const uint4*)(x1 + (size_t)s0.x * 32 + 4 * j);
    uint4 u1 = *(const uint4*)(x1 + (size_t)s1.x * 32 + 4 * j);
    uint4 u2 = *(const uint4*)(x1 + (size_t)s2.x * 32 + 4 * j);
    uint4 u3 = *(const uint4*)(x1 + (size_t)s3.x * 32 + 4 * j);
    fma8_bf(a, v0, u0);
    fma8_bf(a, v1, u1);
    fma8_bf(a, v2, u2);
    fma8_bf(a, v3, u3);
  }
  // layer-2 term: X1 at this row
  uint4 u = *(const uint4*)(x1 + (size_t)rr * 32 + 4 * j);
  float* o1 = out + dst + 4 * j;
  float* o2 = out + dst + 32 + 4 * j;
  float4 t0 = *(float4*)o1;
  float4 t1 = *(float4*)o2;
  t0.x += bf_lo(u.x); t0.y += bf_hi(u.x); t0.z += bf_lo(u.y); t0.w += bf_hi(u.y);
  t1.x += bf_lo(u.z); t1.y += bf_hi(u.z); t1.z += bf_lo(u.w); t1.w += bf_hi(u.w);
  t0.x += a[0]; t0.y += a[1]; t0.z += a[2]; t0.w += a[3];
  t1.x += a[4]; t1.y += a[5]; t1.z += a[6]; t1.w += a[7];
  float ov[8] = {t0.x * 0.25f, t0.y * 0.25f, t0.z * 0.25f, t0.w * 0.25f,
                 t1.x * 0.25f, t1.y * 0.25f, t1.z * 0.25f, t1.w * 0.25f};
  float tv[8];
#pragma unroll
  for (int c = 0; c < 8; ++c) {
    int d = (c < 4) ? (4 * j + c) : (32 + 4 * j + (c - 4));
    bool present = (bits32(mk0, mk1, (uint32_t)(fbase + d)) >> 31) == 0u;
    tv[c] = present ? ov[c] * 2.0f : 0.0f;
  }
  *(float4*)o1 = make_float4(ov[0], ov[1], ov[2], ov[3]);
  *(float4*)o2 = make_float4(ov[4], ov[5], ov[6], ov[7]);
  *(float4*)(o1 + H) = make_float4(tv[0], tv[1], tv[2], tv[3]);
  *(float4*)(o2 + H) = make_float4(tv[4], tv[5], tv[6], tv[7]);
}

extern "C" void kernel_launch(void* const* d_in, const int* in_sizes, int n_in,
                              void* d_out, int out_size, void* d_ws, size_t ws_size,
                              hipStream_t stream) {
  const float* uemb  = (const float*)d_in[0];
  const float* iemb  = (const float*)d_in[1];
  const float* avals = (const float*)d_in[2];
  const int*   rows  = (const int*)d_in[3];
  const int*   cols  = (const int*)d_in[4];
  const int*   users = (const int*)d_in[5];
  const int*   items = (const int*)d_in[6];
  const int DIM = 64;
  const int NU = in_sizes[0] / DIM;
  const int NI = in_sizes[1] / DIM;
  const int E  = in_sizes[2];
  const int E2 = E / 2;             // first half: user rows, sorted by row
  const int B = in_sizes[5];
  const int NN = NU + NI;
  float* out = (float*)d_out;
  (void)n_in; (void)out_size; (void)ws_size;

  uint32_t ke0, ke1, ku0, ku1, ki0, ki1;
  tf2x32(0u, 1234u, 0u, 0u, ke0, ke1);
  tf2x32(0u, 1234u, 0u, 1u, ku0, ku1);
  tf2x32(0u, 1234u, 0u, 2u, ki0, ki1);

  char* p = (char*)d_ws;
  auto carve = [&](size_t bytes) {
    char* r = p;
    p += (bytes + 255) & ~(size_t)255;
    return (void*)r;
  };
  uint32_t* X0    = (uint32_t*)carve((size_t)NN * 32 * 4);  // bf16x2 rows
  uint32_t* X1    = (uint32_t*)carve((size_t)NN * 32 * 4);
  int2*  slot     = (int2*)carve((size_t)E * 8);            // unified u|i
  unsigned long long* keepw = (unsigned long long*)carve(((size_t)E / 64 + 2) * 8);
  int*   cnt      = (int*)carve((size_t)NI * 4);
  int*   row_ptr  = (int*)carve((size_t)(NN + 1) * 4);      // unified
  int*   nextc    = (int*)carve((size_t)NI * 4);
  uint8_t* fB     = (uint8_t*)carve((size_t)NN * 3);  // fB | f1 | f2
  uint8_t* f1     = fB + NN;
  uint8_t* f2     = fB + 2 * (size_t)NN;
  int4*  list1    = (int4*)carve((size_t)NN * 16);
  int4*  list2    = (int4*)carve((size_t)NN * 16);
  const int GK    = (E + 1023) / 1024;
  const int NBE   = (E2 + 1023) / 1024;
  const int NBI   = (NI + 255) / 256;
  const int NB    = (NN + 255) / 256;
  int*   bsumE    = (int*)carve((size_t)GK * 4);
  int*   bprefE   = (int*)carve((size_t)(NBE + 1) * 4);   // bprefE[NBE] = keptU
  int*   bsumI    = (int*)carve((size_t)NBI * 4);
  int*   bprefI   = (int*)carve((size_t)(NBI + 1) * 4);
  int*   bs1      = (int*)carve((size_t)NB * 4);
  int*   bb1      = (int*)carve((size_t)NB * 4);
  int*   bs2      = (int*)carve((size_t)NB * 4);
  int*   bb2      = (int*)carve((size_t)NB * 4);
  int*   ps1      = (int*)carve((size_t)(NB + 1) * 4);    // [NB] = count
  int*   pb1      = (int*)carve((size_t)(NB + 1) * 4);
  int*   ps2      = (int*)carve((size_t)(NB + 1) * 4);
  int*   pb2      = (int*)carve((size_t)(NB + 1) * 4);

  hipMemsetAsync(cnt, 0, (size_t)NI * 4, stream);
  hipMemsetAsync(fB, 0, (size_t)NN * 3, stream);

  // CSR build (unified slot array) + batch marking
  k_keep<<<GK, 1024, 0, stream>>>(rows, E, E2, NU, keepw, bsumE, cnt,
                                  users, items, B, fB, f1, f2, ke0, ke1);
  k_blocksum<<<NBI, 256, 0, stream>>>(cnt, NI, bsumI);
  k_scanb2x<<<1, 1024, 0, stream>>>(bsumE, NBE, bprefE, bsumI, NBI, bprefI);
  k_scan_write<<<NBI, 256, 0, stream>>>(cnt, NI, bprefI, bprefE + NBE,
                                        row_ptr + NU, nextc);
  k_compactU<<<NBE, 1024, 0, stream>>>(rows, cols, avals, keepw, bprefE, E2, NU, NBE,
                                       slot, row_ptr);
  {
    const int gI = (E - E2 + 255) / 256;
    k_scatterI<<<gI, 256, 0, stream>>>(rows, cols, avals, keepw, E, E2, NU, nextc, slot);
  }

  // frontier: f2 = batch u N(batch); f1 = batch u N(f2); degree-bucketed lists
  const int gN = (NN + 255) / 256;
  k_mark_neighbors<<<gN, 256, 0, stream>>>(fB, row_ptr, slot, NN, f2);
  k_mark_neighbors<<<gN, 256, 0, stream>>>(f2, row_ptr, slot, NN, f1);
  k_flagsum4<<<NB, 256, 0, stream>>>(f1, f2, row_ptr, NN, bs1, bb1, bs2, bb2);
  k_scanb4<<<1, 1024, 0, stream>>>(bs1, ps1, bb1, pb1, bs2, ps2, bb2, pb2, NB);
  k_compact4<<<NB, 256, 0, stream>>>(f1, f2, row_ptr, NN, NB, ps1, pb1, ps2, pb2,
                                     list1, list2);

  const int gG = (2 * B + 31) / 32;
  const int gS = (NN + 31) / 32;      // upper bound; spmm exits past nrows

  // layer 1: X0 = A * emb (rows in f1)
  k_spmm<1><<<gS, 256, 0, stream>>>(slot, X1, uemb, iemb, X0, list1,
                                    ps1 + NB, pb1 + NB, NU);
  // out_online = emb + X0 at batch rows (pure write)
  k_gatherA<<<gG, 256, 0, stream>>>(X0, uemb, iemb, users, items, out, B, NU);
  // layer 2: X1 = A * X0 (rows in f2)
  k_spmm<0><<<gS, 256, 0, stream>>>(slot, X0, uemb, iemb, X1, list2,
                                    ps2 + NB, pb2 + NB, NU);
  // tail: += X1 (L2) + A*X1 (L3), /4, target masks
  k_tail<<<gG, 256, 0, stream>>>(row_ptr, slot, X1, users, items, out, B, NU,
                                 ku0, ku1, ki0, ki1);
}

// Round 10
// 166.016 us; speedup vs baseline: 1.0407x; 1.0407x over previous
//
#include <hip/hip_runtime.h>
#include <stdint.h>

// ---------------- JAX threefry2x32 (partitionable mode) ----------------
__host__ __device__ inline void tf2x32(uint32_t k0, uint32_t k1,
                                       uint32_t x0, uint32_t x1,
                                       uint32_t& o0, uint32_t& o1) {
  const uint32_t ks2 = k0 ^ k1 ^ 0x1BD11BDAu;
  x0 += k0; x1 += k1;
#define TFR(r) { x0 += x1; x1 = (x1 << (r)) | (x1 >> (32 - (r))); x1 ^= x0; }
  TFR(13) TFR(15) TFR(26) TFR(6)
  x0 += k1;  x1 += ks2 + 1u;
  TFR(17) TFR(29) TFR(16) TFR(24)
  x0 += ks2; x1 += k0 + 2u;
  TFR(13) TFR(15) TFR(26) TFR(6)
  x0 += k0;  x1 += k1 + 3u;
  TFR(17) TFR(29) TFR(16) TFR(24)
  x0 += k1;  x1 += ks2 + 4u;
  TFR(13) TFR(15) TFR(26) TFR(6)
  x0 += ks2; x1 += k0 + 5u;
#undef TFR
  o0 = x0; o1 = x1;
}

__host__ __device__ inline uint32_t bits32(uint32_t k0, uint32_t k1, uint32_t idx) {
  uint32_t a, b;
  tf2x32(k0, k1, 0u, idx, a, b);
  return a ^ b;
}

// keep-edge iff uniform >= 0.5 iff bit31 of bits set (floor(0.5+u) == 1)
__device__ inline bool edge_kept(uint32_t k0, uint32_t k1, uint32_t e) {
  return (bits32(k0, k1, e) >> 31) != 0u;
}

__device__ inline float bf_lo(uint32_t u) { return __uint_as_float(u << 16); }
__device__ inline float bf_hi(uint32_t u) { return __uint_as_float(u & 0xffff0000u); }
__device__ inline uint32_t bf_pack(float a, float b) {
  uint32_t lo = (__float_as_uint(a) + 0x8000u) >> 16;
  uint32_t hi = (__float_as_uint(b) + 0x8000u) & 0xffff0000u;
  return hi | lo;
}

__device__ inline void fma8_bf(float a[8], float v, const uint4& u) {
  a[0] = fmaf(v, bf_lo(u.x), a[0]); a[1] = fmaf(v, bf_hi(u.x), a[1]);
  a[2] = fmaf(v, bf_lo(u.y), a[2]); a[3] = fmaf(v, bf_hi(u.y), a[3]);
  a[4] = fmaf(v, bf_lo(u.z), a[4]); a[5] = fmaf(v, bf_hi(u.z), a[5]);
  a[6] = fmaf(v, bf_lo(u.w), a[6]); a[7] = fmaf(v, bf_hi(u.w), a[7]);
}

// ---------------- init: clear cnt + flags in one dispatch ----------------
__global__ void k_clear(int* __restrict__ cnt, int ni,
                        uint32_t* __restrict__ f, int fwords) {
  int i = blockIdx.x * 256 + threadIdx.x;
  if (i < ni) cnt[i] = 0;
  int k = i - ni;
  if (k >= 0 && k < fwords) f[k] = 0;
}

// ---------------- embeddings -> bf16x2 packed rows (coalesced stream) ------
__global__ void k_tobf16(const float* __restrict__ uemb, const float* __restrict__ iemb,
                         uint32_t* __restrict__ xe, int nu, int nn) {
  int i = blockIdx.x * 256 + threadIdx.x;   // one uint4 (8 dims) per thread
  if (i >= nn * 8) return;
  int r = i >> 3, q = i & 7;
  const float* p = (r < nu) ? uemb + (size_t)r * 64 : iemb + (size_t)(r - nu) * 64;
  float4 f0 = *(const float4*)(p + 8 * q);
  float4 f1 = *(const float4*)(p + 8 * q + 4);
  uint4 o;
  o.x = bf_pack(f0.x, f0.y); o.y = bf_pack(f0.z, f0.w);
  o.z = bf_pack(f1.x, f1.y); o.w = bf_pack(f1.z, f1.w);
  *(uint4*)(xe + (size_t)r * 32 + 4 * q) = o;
}

// ---------------- keep bits: packed mask + first-half block sums +
//                  item-half per-row counts, all in one pass ----------------
__global__ __launch_bounds__(1024) void k_keep(
    const int* __restrict__ rows, int E, int E2, int nu,
    unsigned long long* __restrict__ keepw, int* __restrict__ bsumE,
    int* __restrict__ cnt, uint32_t ke0, uint32_t ke1) {
  __shared__ int s[16];
  int e = blockIdx.x * 1024 + threadIdx.x;
  int lane = threadIdx.x & 63;
  int wid = threadIdx.x >> 6;
  bool kept = (e < E) && edge_kept(ke0, ke1, (uint32_t)e);
  unsigned long long m = __ballot(kept);
  int ws = blockIdx.x * 1024 + wid * 64;
  if (lane == 0 && ws < E) keepw[ws >> 6] = m;
  int nf = 0;
  if (ws + 64 <= E2) nf = __popcll(m);
  else if (ws < E2) nf = __popcll(m & ((1ull << (E2 - ws)) - 1ull));
  if (lane == 0) s[wid] = nf;
  __syncthreads();
  if (threadIdx.x == 0) {
    int t = 0;
    for (int i = 0; i < 16; ++i) t += s[i];
    bsumE[blockIdx.x] = t;
  }
  if (kept && e >= E2) atomicAdd(&cnt[rows[e] - nu], 1);
}

// single block, 1024 threads, scans up to 2048 block sums -> exclusive prefix
__device__ inline void scan_block_1024(const int* __restrict__ bsum, int nb,
                                       int* __restrict__ bpref,
                                       int* a, int* b) {
  int t = threadIdx.x;
  for (int i = t; i < 2048; i += 1024) a[i] = (i < nb) ? bsum[i] : 0;
  __syncthreads();
  int* cur = a; int* nxt = b;
  for (int off = 1; off < 2048; off <<= 1) {
    for (int i = t; i < 2048; i += 1024)
      nxt[i] = cur[i] + (i >= off ? cur[i - off] : 0);
    __syncthreads();
    int* tmp = cur; cur = nxt; nxt = tmp;
  }
  for (int i = t; i <= nb; i += 1024)
    bpref[i] = (i == 0) ? 0 : cur[i - 1];
  __syncthreads();
}

__global__ void k_scanb2x(const int* __restrict__ bA, int nA, int* __restrict__ pA,
                          const int* __restrict__ bB, int nB, int* __restrict__ pB) {
  __shared__ int a[2048], b[2048];
  scan_block_1024(bA, nA, pA, a, b);
  scan_block_1024(bB, nB, pB, a, b);
}

__global__ void k_blocksum(const int* __restrict__ cnt, int n, int* __restrict__ bsum) {
  __shared__ int s[256];
  int i = blockIdx.x * 256 + threadIdx.x;
  s[threadIdx.x] = (i < n) ? cnt[i] : 0;
  __syncthreads();
  for (int off = 128; off > 0; off >>= 1) {
    if (threadIdx.x < off) s[threadIdx.x] += s[threadIdx.x + off];
    __syncthreads();
  }
  if (threadIdx.x == 0) bsum[blockIdx.x] = s[0];
}

__global__ void k_scan_write(const int* __restrict__ cnt, int n, const int* __restrict__ bpref,
                             int* __restrict__ row_ptr, int* __restrict__ nextc) {
  __shared__ int a[256], b[256];
  int t = threadIdx.x;
  int i = blockIdx.x * 256 + t;
  int v = (i < n) ? cnt[i] : 0;
  a[t] = v;
  __syncthreads();
  int* cur = a; int* nxt = b;
  for (int off = 1; off < 256; off <<= 1) {
    nxt[t] = cur[t] + (t >= off ? cur[t - off] : 0);
    __syncthreads();
    int* tmp = cur; cur = nxt; nxt = tmp;
  }
  int incl = cur[t] + bpref[blockIdx.x];
  int excl = incl - v;
  if (i < n) { row_ptr[i] = excl; nextc[i] = excl; }
  if (i == n - 1) row_ptr[n] = incl;
}

// ---- user-half compaction: coalesced writes (kept edges stay row-sorted),
//      row_ptr_u from boundaries of the sorted rows array. Deterministic. ----
__global__ __launch_bounds__(1024) void k_compactU(
    const int* __restrict__ rows, const int* __restrict__ cols,
    const float* __restrict__ avals, const unsigned long long* __restrict__ keepw,
    const int* __restrict__ bprefE, int E2, int nu, int nbE,
    int2* __restrict__ uslot, int* __restrict__ row_ptr_u) {
  __shared__ int a[1024], b[1024];
  int t = threadIdx.x;
  int e = blockIdx.x * 1024 + t;
  bool kept = (e < E2) && ((keepw[e >> 6] >> (e & 63)) & 1ull);
  a[t] = kept ? 1 : 0;
  __syncthreads();
  int* cur = a; int* nxt = b;
  for (int off = 1; off < 1024; off <<= 1) {
    nxt[t] = cur[t] + (t >= off ? cur[t - off] : 0);
    __syncthreads();
    int* tmp = cur; cur = nxt; nxt = tmp;
  }
  int excl = cur[t] - (kept ? 1 : 0);
  int pos = bprefE[blockIdx.x] + excl;
  if (kept) uslot[pos] = make_int2(cols[e], __float_as_int(avals[e] * 2.0f));
  if (e < E2) {
    int r = rows[e];
    int rp = (e == 0) ? -1 : rows[e - 1];
    for (int rr = rp + 1; rr <= r; ++rr) row_ptr_u[rr] = pos;
    if (e == E2 - 1) {
      int total = bprefE[nbE];
      for (int rr = r + 1; rr <= nu; ++rr) row_ptr_u[rr] = total;
    }
  }
}

// ---- item-half scatter (small: ~kept/2 random 8B writes into ~4MB) ----
__global__ void k_scatterI(const int* __restrict__ rows, const int* __restrict__ cols,
                           const float* __restrict__ avals,
                           const unsigned long long* __restrict__ keepw,
                           int E, int E2, int nu, int* __restrict__ nextc,
                           int2* __restrict__ islot) {
  int e = E2 + blockIdx.x * 256 + threadIdx.x;
  if (e >= E) return;
  if (!((keepw[e >> 6] >> (e & 63)) & 1ull)) return;
  int r = rows[e] - nu;
  int k = atomicAdd(&nextc[r], 1);
  islot[k] = make_int2(cols[e], __float_as_int(avals[e] * 2.0f));
}

// ---------------- frontier marking + scan-based compaction ----------------
__global__ void k_mark_batch(const int* __restrict__ users, const int* __restrict__ items,
                             int batch, int nu, uint8_t* fB, uint8_t* f1, uint8_t* f2) {
  int i = blockIdx.x * 256 + threadIdx.x;
  if (i >= 2 * batch) return;
  int r = (i < batch) ? users[i] : nu + items[i - batch];
  fB[r] = 1; f1[r] = 1; f2[r] = 1;
}

__global__ void k_mark_neighbors(const uint8_t* __restrict__ fin,
                                 const int* __restrict__ row_ptr_u,
                                 const int2* __restrict__ uslot,
                                 const int* __restrict__ row_ptr_i,
                                 const int2* __restrict__ islot,
                                 int n, int nu, uint8_t* __restrict__ fout) {
  int r = blockIdx.x * 256 + threadIdx.x;
  if (r >= n) return;
  if (!fin[r]) return;
  const int* rp = (r < nu) ? row_ptr_u : row_ptr_i;
  const int2* sl = (r < nu) ? uslot : islot;
  int rr = (r < nu) ? r : r - nu;
  int s = rp[rr], e = rp[rr + 1];
  for (int k = s; k < e; ++k) fout[sl[k].x] = 1;
}

__global__ void k_flagsum2(const uint8_t* __restrict__ f1, const uint8_t* __restrict__ f2,
                           int n, int* __restrict__ bsum1, int* __restrict__ bsum2) {
  __shared__ int s1[256], s2[256];
  int i = blockIdx.x * 256 + threadIdx.x;
  s1[threadIdx.x] = (i < n) ? (int)f1[i] : 0;
  s2[threadIdx.x] = (i < n) ? (int)f2[i] : 0;
  __syncthreads();
  for (int off = 128; off > 0; off >>= 1) {
    if (threadIdx.x < off) {
      s1[threadIdx.x] += s1[threadIdx.x + off];
      s2[threadIdx.x] += s2[threadIdx.x + off];
    }
    __syncthreads();
  }
  if (threadIdx.x == 0) { bsum1[blockIdx.x] = s1[0]; bsum2[blockIdx.x] = s2[0]; }
}

__global__ void k_compact2(const uint8_t* __restrict__ f1, const uint8_t* __restrict__ f2,
                           int n, const int* __restrict__ bpref1,
                           const int* __restrict__ bpref2,
                           int* __restrict__ list1, int* __restrict__ list2) {
  __shared__ int a[256], b[256];
  int t = threadIdx.x;
  int i = blockIdx.x * 256 + t;

  int v = (i < n) ? (int)f1[i] : 0;
  a[t] = v;
  __syncthreads();
  int* cur = a; int* nxt = b;
  for (int off = 1; off < 256; off <<= 1) {
    nxt[t] = cur[t] + (t >= off ? cur[t - off] : 0);
    __syncthreads();
    int* tmp = cur; cur = nxt; nxt = tmp;
  }
  if (v) list1[bpref1[blockIdx.x] + cur[t] - 1] = i;
  __syncthreads();

  v = (i < n) ? (int)f2[i] : 0;
  a[t] = v;
  __syncthreads();
  cur = a; nxt = b;
  for (int off = 1; off < 256; off <<= 1) {
    nxt[t] = cur[t] + (t >= off ? cur[t - off] : 0);
    __syncthreads();
    int* tmp = cur; cur = nxt; nxt = tmp;
  }
  if (v) list2[bpref2[blockIdx.x] + cur[t] - 1] = i;
}

// -------- SPMM: 8 lanes per row (lane owns 8 dims), 4-edge unroll,
//          bf16x2-packed input and output rows --------
__global__ __launch_bounds__(256) void k_spmm(
    const int* __restrict__ row_ptr_u, const int2* __restrict__ uslot,
    const int* __restrict__ row_ptr_i, const int2* __restrict__ islot,
    const uint32_t* __restrict__ xin, uint32_t* __restrict__ xout,
    const int* __restrict__ rowlist, const int* __restrict__ nrows_p, int nu) {
  int nrows = *nrows_p;
  int i = blockIdx.x * 32 + (threadIdx.x >> 3);
  if (i >= nrows) return;
  int r = rowlist[i];
  int j = threadIdx.x & 7;
  bool isu = r < nu;
  const int* rp = isu ? row_ptr_u : row_ptr_i;
  const int2* sl = isu ? uslot : islot;
  int rr = isu ? r : r - nu;
  int s = rp[rr], e = rp[rr + 1];
  float a[8] = {0, 0, 0, 0, 0, 0, 0, 0};
  int last = e - 1;
  for (int k = s; k < e; k += 4) {
    int i1 = (k + 1 <= last) ? k + 1 : last;
    int i2 = (k + 2 <= last) ? k + 2 : last;
    int i3 = (k + 3 <= last) ? k + 3 : last;
    int2 s0 = sl[k], s1 = sl[i1], s2 = sl[i2], s3 = sl[i3];
    float v0 = __int_as_float(s0.y);
    float v1 = (k + 1 <= last) ? __int_as_float(s1.y) : 0.0f;
    float v2 = (k + 2 <= last) ? __int_as_float(s2.y) : 0.0f;
    float v3 = (k + 3 <= last) ? __int_as_float(s3.y) : 0.0f;
    uint4 u0 = *(const uint4*)(xin + (size_t)s0.x * 32 + 4 * j);
    uint4 u1 = *(const uint4*)(xin + (size_t)s1.x * 32 + 4 * j);
    uint4 u2 = *(const uint4*)(xin + (size_t)s2.x * 32 + 4 * j);
    uint4 u3 = *(const uint4*)(xin + (size_t)s3.x * 32 + 4 * j);
    fma8_bf(a, v0, u0);
    fma8_bf(a, v1, u1);
    fma8_bf(a, v2, u2);
    fma8_bf(a, v3, u3);
  }
  uint4 o;
  o.x = bf_pack(a[0], a[1]); o.y = bf_pack(a[2], a[3]);
  o.z = bf_pack(a[4], a[5]); o.w = bf_pack(a[6], a[7]);
  *(uint4*)(xout + (size_t)r * 32 + 4 * j) = o;
}

// ---- epilogue A (after layer 1): out_online = emb[row] + bf(X0[row]) ----
// out layout: [u_online | u_target | i_online | i_target], H = B*64 each.
__global__ void k_gatherA(const uint32_t* __restrict__ x0, const float* __restrict__ uemb,
                          const float* __restrict__ iemb, const int* __restrict__ users,
                          const int* __restrict__ items, float* __restrict__ out,
                          int batch, int nu) {
  int b = blockIdx.x * 32 + (threadIdx.x >> 3);
  if (b >= 2 * batch) return;
  int j = threadIdx.x & 7;
  size_t H = (size_t)batch * 64;
  int row; size_t dst; bool isu = b < batch;
  if (isu) {
    row = users[b];
    dst = (size_t)b * 64 + 8 * j;
  } else {
    int bi = b - batch;
    row = items[bi];
    dst = 2 * H + (size_t)bi * 64 + 8 * j;
  }
  const float* p = (isu ? uemb + (size_t)row * 64 : iemb + (size_t)row * 64) + 8 * j;
  float4 t0 = *(const float4*)p;
  float4 t1 = *(const float4*)(p + 4);
  int xr = isu ? row : nu + row;
  uint4 u = *(const uint4*)(x0 + (size_t)xr * 32 + 4 * j);
  t0.x += bf_lo(u.x); t0.y += bf_hi(u.x); t0.z += bf_lo(u.y); t0.w += bf_hi(u.y);
  t1.x += bf_lo(u.z); t1.y += bf_hi(u.z); t1.z += bf_lo(u.w); t1.w += bf_hi(u.w);
  *(float4*)(out + dst) = t0;
  *(float4*)(out + dst + 4) = t1;
}

// ---- epilogue tail: += bf(X1[row]) [L2] + SPMM(X1)[row] [L3], /4, masks ----
__global__ __launch_bounds__(256) void k_tail(
    const int* __restrict__ row_ptr_u, const int2* __restrict__ uslot,
    const int* __restrict__ row_ptr_i, const int2* __restrict__ islot,
    const uint32_t* __restrict__ x1, const int* __restrict__ users,
    const int* __restrict__ items, float* __restrict__ out,
    int batch, int nu,
    uint32_t ku0, uint32_t ku1, uint32_t ki0, uint32_t ki1) {
  int b = blockIdx.x * 32 + (threadIdx.x >> 3);
  if (b >= 2 * batch) return;
  int j = threadIdx.x & 7;
  size_t H = (size_t)batch * 64;
  const int* rp; const int2* sl; int rr; size_t dst; int f0; uint32_t mk0, mk1;
  bool isu = b < batch;
  if (isu) {
    rr = users[b];
    rp = row_ptr_u; sl = uslot;
    dst = (size_t)b * 64 + 8 * j;
    f0 = b * 64 + 8 * j;
    mk0 = ku0; mk1 = ku1;
  } else {
    int bi = b - batch;
    rr = items[bi];
    rp = row_ptr_i; sl = islot;
    dst = 2 * H + (size_t)bi * 64 + 8 * j;
    f0 = bi * 64 + 8 * j;
    mk0 = ki0; mk1 = ki1;
  }
  int s = rp[rr], e = rp[rr + 1];
  float a[8] = {0, 0, 0, 0, 0, 0, 0, 0};
  int last = e - 1;
  for (int k = s; k < e; k += 4) {
    int i1 = (k + 1 <= last) ? k + 1 : last;
    int i2 = (k + 2 <= last) ? k + 2 : last;
    int i3 = (k + 3 <= last) ? k + 3 : last;
    int2 s0 = sl[k], s1 = sl[i1], s2 = sl[i2], s3 = sl[i3];
    float v0 = __int_as_float(s0.y);
    float v1 = (k + 1 <= last) ? __int_as_float(s1.y) : 0.0f;
    float v2 = (k + 2 <= last) ? __int_as_float(s2.y) : 0.0f;
    float v3 = (k + 3 <= last) ? __int_as_float(s3.y) : 0.0f;
    uint4 u0 = *(const uint4*)(x1 + (size_t)s0.x * 32 + 4 * j);
    uint4 u1 = *(const uint4*)(x1 + (size_t)s1.x * 32 + 4 * j);
    uint4 u2 = *(const uint4*)(x1 + (size_t)s2.x * 32 + 4 * j);
    uint4 u3 = *(const uint4*)(x1 + (size_t)s3.x * 32 + 4 * j);
    fma8_bf(a, v0, u0);
    fma8_bf(a, v1, u1);
    fma8_bf(a, v2, u2);
    fma8_bf(a, v3, u3);
  }
  // layer-2 term: X1 at this row
  int xr = isu ? rr : nu + rr;
  uint4 u = *(const uint4*)(x1 + (size_t)xr * 32 + 4 * j);
  float* o = out + dst;
  float4 t0 = *(float4*)o;
  float4 t1 = *(float4*)(o + 4);
  t0.x += bf_lo(u.x); t0.y += bf_hi(u.x); t0.z += bf_lo(u.y); t0.w += bf_hi(u.y);
  t1.x += bf_lo(u.z); t1.y += bf_hi(u.z); t1.z += bf_lo(u.w); t1.w += bf_hi(u.w);
  t0.x += a[0]; t0.y += a[1]; t0.z += a[2]; t0.w += a[3];
  t1.x += a[4]; t1.y += a[5]; t1.z += a[6]; t1.w += a[7];
  float ov[8] = {t0.x * 0.25f, t0.y * 0.25f, t0.z * 0.25f, t0.w * 0.25f,
                 t1.x * 0.25f, t1.y * 0.25f, t1.z * 0.25f, t1.w * 0.25f};
  float tv[8];
#pragma unroll
  for (int c = 0; c < 8; ++c) {
    bool present = (bits32(mk0, mk1, (uint32_t)(f0 + c)) >> 31) == 0u;
    tv[c] = present ? ov[c] * 2.0f : 0.0f;
  }
  *(float4*)o = make_float4(ov[0], ov[1], ov[2], ov[3]);
  *(float4*)(o + 4) = make_float4(ov[4], ov[5], ov[6], ov[7]);
  *(float4*)(o + H) = make_float4(tv[0], tv[1], tv[2], tv[3]);
  *(float4*)(o + H + 4) = make_float4(tv[4], tv[5], tv[6], tv[7]);
}

extern "C" void kernel_launch(void* const* d_in, const int* in_sizes, int n_in,
                              void* d_out, int out_size, void* d_ws, size_t ws_size,
                              hipStream_t stream) {
  const float* uemb  = (const float*)d_in[0];
  const float* iemb  = (const float*)d_in[1];
  const float* avals = (const float*)d_in[2];
  const int*   rows  = (const int*)d_in[3];
  const int*   cols  = (const int*)d_in[4];
  const int*   users = (const int*)d_in[5];
  const int*   items = (const int*)d_in[6];
  const int DIM = 64;
  const int NU = in_sizes[0] / DIM;
  const int NI = in_sizes[1] / DIM;
  const int E  = in_sizes[2];
  const int E2 = E / 2;             // first half: user rows, sorted by row
  const int B = in_sizes[5];
  const int NN = NU + NI;
  float* out = (float*)d_out;
  (void)n_in; (void)out_size; (void)ws_size;

  // derived subkeys: split(key(1234), 3) fold-like = threefry(key, (0, i))
  uint32_t ke0, ke1, ku0, ku1, ki0, ki1;
  tf2x32(0u, 1234u, 0u, 0u, ke0, ke1);
  tf2x32(0u, 1234u, 0u, 1u, ku0, ku1);
  tf2x32(0u, 1234u, 0u, 2u, ki0, ki1);

  // workspace carve
  char* p = (char*)d_ws;
  auto carve = [&](size_t bytes) {
    char* r = p;
    p += (bytes + 255) & ~(size_t)255;
    return (void*)r;
  };
  uint32_t* Xe    = (uint32_t*)carve((size_t)NN * 32 * 4);  // bf16 embeddings
  uint32_t* X0    = (uint32_t*)carve((size_t)NN * 32 * 4);  // bf16x2 rows
  uint32_t* X1    = (uint32_t*)carve((size_t)NN * 32 * 4);
  int2*  uslot    = (int2*)carve((size_t)E2 * 8);
  int2*  islot    = (int2*)carve((size_t)(E - E2) * 8);
  unsigned long long* keepw = (unsigned long long*)carve(((size_t)E / 64 + 2) * 8);
  int*   cnt      = (int*)carve((size_t)NI * 4);
  int*   row_ptr_u = (int*)carve((size_t)(NU + 1) * 4);
  int*   row_ptr_i = (int*)carve((size_t)(NI + 1) * 4);
  int*   nextc    = (int*)carve((size_t)NI * 4);
  uint8_t* fB     = (uint8_t*)carve((size_t)NN * 3);  // fB | f1 | f2
  uint8_t* f1     = fB + NN;
  uint8_t* f2     = fB + 2 * (size_t)NN;
  int*   list1    = (int*)carve((size_t)NN * 4);
  int*   list2    = (int*)carve((size_t)NN * 4);
  const int GK    = (E + 1023) / 1024;
  const int NBE   = (E2 + 1023) / 1024;
  const int NBI   = (NI + 255) / 256;
  const int NB    = (NN + 255) / 256;
  int*   bsumE    = (int*)carve((size_t)GK * 4);
  int*   bprefE   = (int*)carve((size_t)(NBE + 1) * 4);
  int*   bsumI    = (int*)carve((size_t)NBI * 4);
  int*   bprefI   = (int*)carve((size_t)(NBI + 1) * 4);
  int*   bsum1    = (int*)carve((size_t)NB * 4);
  int*   bpref1   = (int*)carve((size_t)(NB + 1) * 4);   // bpref1[NB] = |list1|
  int*   bsum2    = (int*)carve((size_t)NB * 4);
  int*   bpref2   = (int*)carve((size_t)(NB + 1) * 4);   // bpref2[NB] = |list2|

  // clear cnt + flags (one dispatch, replaces two hipMemsetAsync)
  {
    const int fwords = (int)(((size_t)NN * 3 + 3) / 4);   // within 256B-padded carve
    const int gC = (NI + fwords + 255) / 256;
    k_clear<<<gC, 256, 0, stream>>>(cnt, NI, (uint32_t*)fB, fwords);
  }
  // embeddings -> bf16 (coalesced stream; used by layer-1 spmm)
  k_tobf16<<<(NN * 8 + 255) / 256, 256, 0, stream>>>(uemb, iemb, Xe, NU, NN);

  // CSR build: deterministic coalesced compaction (user half, row-sorted) +
  // small atomic scatter (item half)
  k_keep<<<GK, 1024, 0, stream>>>(rows, E, E2, NU, keepw, bsumE, cnt, ke0, ke1);
  k_blocksum<<<NBI, 256, 0, stream>>>(cnt, NI, bsumI);
  k_scanb2x<<<1, 1024, 0, stream>>>(bsumE, NBE, bprefE, bsumI, NBI, bprefI);
  k_scan_write<<<NBI, 256, 0, stream>>>(cnt, NI, bprefI, row_ptr_i, nextc);
  k_compactU<<<NBE, 1024, 0, stream>>>(rows, cols, avals, keepw, bprefE, E2, NU, NBE,
                                       uslot, row_ptr_u);
  {
    const int gI = (E - E2 + 255) / 256;
    k_scatterI<<<gI, 256, 0, stream>>>(rows, cols, avals, keepw, E, E2, NU, nextc, islot);
  }

  // frontier: f2 = batch ∪ N(batch); f1 = batch ∪ N(f2); scan-compact to lists
  const int gB = (2 * B + 255) / 256;
  const int gN = (NN + 255) / 256;
  k_mark_batch<<<gB, 256, 0, stream>>>(users, items, B, NU, fB, f1, f2);
  k_mark_neighbors<<<gN, 256, 0, stream>>>(fB, row_ptr_u, uslot, row_ptr_i, islot, NN, NU, f2);
  k_mark_neighbors<<<gN, 256, 0, stream>>>(f2, row_ptr_u, uslot, row_ptr_i, islot, NN, NU, f1);
  k_flagsum2<<<NB, 256, 0, stream>>>(f1, f2, NN, bsum1, bsum2);
  k_scanb2x<<<1, 1024, 0, stream>>>(bsum1, NB, bpref1, bsum2, NB, bpref2);
  k_compact2<<<NB, 256, 0, stream>>>(f1, f2, NN, bpref1, bpref2, list1, list2);

  const int gG = (2 * B + 31) / 32;   // 32 batch slots/block (8 lanes each)
  const int gS = (NN + 31) / 32;      // upper bound; spmm exits past nrows

  // layer 1: X0 = A * bf16(emb) (rows in f1)
  k_spmm<<<gS, 256, 0, stream>>>(row_ptr_u, uslot, row_ptr_i, islot, Xe, X0,
                                 list1, bpref1 + NB, NU);
  // out_online = emb + X0 at batch rows (pure write)
  k_gatherA<<<gG, 256, 0, stream>>>(X0, uemb, iemb, users, items, out, B, NU);
  // layer 2: X1 = A * X0 (rows in f2)
  k_spmm<<<gS, 256, 0, stream>>>(row_ptr_u, uslot, row_ptr_i, islot, X0, X1,
                                 list2, bpref2 + NB, NU);
  // tail: += X1 (L2) + A*X1 (L3), /4, target masks — one RMW pass
  k_tail<<<gG, 256, 0, stream>>>(row_ptr_u, uslot, row_ptr_i, islot, X1,
                                 users, items, out, B, NU, ku0, ku1, ki0, ki1);
}

// Round 11
// 156.991 us; speedup vs baseline: 1.1006x; 1.0575x over previous
//
#include <hip/hip_runtime.h>
#include <stdint.h>

// ---------------- JAX threefry2x32 (partitionable mode) ----------------
__host__ __device__ inline void tf2x32(uint32_t k0, uint32_t k1,
                                       uint32_t x0, uint32_t x1,
                                       uint32_t& o0, uint32_t& o1) {
  const uint32_t ks2 = k0 ^ k1 ^ 0x1BD11BDAu;
  x0 += k0; x1 += k1;
#define TFR(r) { x0 += x1; x1 = (x1 << (r)) | (x1 >> (32 - (r))); x1 ^= x0; }
  TFR(13) TFR(15) TFR(26) TFR(6)
  x0 += k1;  x1 += ks2 + 1u;
  TFR(17) TFR(29) TFR(16) TFR(24)
  x0 += ks2; x1 += k0 + 2u;
  TFR(13) TFR(15) TFR(26) TFR(6)
  x0 += k0;  x1 += k1 + 3u;
  TFR(17) TFR(29) TFR(16) TFR(24)
  x0 += k1;  x1 += ks2 + 4u;
  TFR(13) TFR(15) TFR(26) TFR(6)
  x0 += ks2; x1 += k0 + 5u;
#undef TFR
  o0 = x0; o1 = x1;
}

__host__ __device__ inline uint32_t bits32(uint32_t k0, uint32_t k1, uint32_t idx) {
  uint32_t a, b;
  tf2x32(k0, k1, 0u, idx, a, b);
  return a ^ b;
}

// keep-edge iff uniform >= 0.5 iff bit31 of bits set (floor(0.5+u) == 1)
__device__ inline bool edge_kept(uint32_t k0, uint32_t k1, uint32_t e) {
  return (bits32(k0, k1, e) >> 31) != 0u;
}

__device__ inline float bf_lo(uint32_t u) { return __uint_as_float(u << 16); }
__device__ inline float bf_hi(uint32_t u) { return __uint_as_float(u & 0xffff0000u); }
__device__ inline uint32_t bf_pack(float a, float b) {
  uint32_t lo = (__float_as_uint(a) + 0x8000u) >> 16;
  uint32_t hi = (__float_as_uint(b) + 0x8000u) & 0xffff0000u;
  return hi | lo;
}

__device__ inline void fma8_bf(float a[8], float v, const uint4& u) {
  a[0] = fmaf(v, bf_lo(u.x), a[0]); a[1] = fmaf(v, bf_hi(u.x), a[1]);
  a[2] = fmaf(v, bf_lo(u.y), a[2]); a[3] = fmaf(v, bf_hi(u.y), a[3]);
  a[4] = fmaf(v, bf_lo(u.z), a[4]); a[5] = fmaf(v, bf_hi(u.z), a[5]);
  a[6] = fmaf(v, bf_lo(u.w), a[6]); a[7] = fmaf(v, bf_hi(u.w), a[7]);
}

// -------- init: clear cnt + flags, and emb->bf16x2 stream, one dispatch ----
__global__ void k_init(int* __restrict__ cnt, int ni,
                       uint32_t* __restrict__ flagw, int fw,
                       const float* __restrict__ uemb, const float* __restrict__ iemb,
                       uint32_t* __restrict__ xe, int nu, int nn) {
  int i = blockIdx.x * 256 + threadIdx.x;
  if (i < ni) { cnt[i] = 0; return; }
  i -= ni;
  if (i < fw) { flagw[i] = 0; return; }
  i -= fw;
  if (i >= nn * 8) return;
  int r = i >> 3, q = i & 7;
  const float* p = (r < nu) ? uemb + (size_t)r * 64 : iemb + (size_t)(r - nu) * 64;
  float4 f0 = *(const float4*)(p + 8 * q);
  float4 f1 = *(const float4*)(p + 8 * q + 4);
  uint4 o;
  o.x = bf_pack(f0.x, f0.y); o.y = bf_pack(f0.z, f0.w);
  o.z = bf_pack(f1.x, f1.y); o.w = bf_pack(f1.z, f1.w);
  *(uint4*)(xe + (size_t)r * 32 + 4 * q) = o;
}

// ---------------- keep bits + first-half block sums + item counts +
//                  batch marking, one pass ----------------
__global__ __launch_bounds__(1024) void k_keep(
    const int* __restrict__ rows, int E, int E2, int nu,
    unsigned long long* __restrict__ keepw, int* __restrict__ bsumE,
    int* __restrict__ cnt, const int* __restrict__ users,
    const int* __restrict__ items, int batch,
    uint8_t* __restrict__ fB, uint8_t* __restrict__ f2,
    uint32_t ke0, uint32_t ke1) {
  __shared__ int s[16];
  int e = blockIdx.x * 1024 + threadIdx.x;
  int lane = threadIdx.x & 63;
  int wid = threadIdx.x >> 6;
  bool kept = (e < E) && edge_kept(ke0, ke1, (uint32_t)e);
  unsigned long long m = __ballot(kept);
  int ws = blockIdx.x * 1024 + wid * 64;
  if (lane == 0 && ws < E) keepw[ws >> 6] = m;
  int nf = 0;
  if (ws + 64 <= E2) nf = __popcll(m);
  else if (ws < E2) nf = __popcll(m & ((1ull << (E2 - ws)) - 1ull));
  if (lane == 0) s[wid] = nf;
  __syncthreads();
  if (threadIdx.x == 0) {
    int t = 0;
    for (int i = 0; i < 16; ++i) t += s[i];
    bsumE[blockIdx.x] = t;
  }
  if (kept && e >= E2) atomicAdd(&cnt[rows[e] - nu], 1);
  // batch marking (first blocks cover 2*batch)
  if (e < 2 * batch) {
    int r = (e < batch) ? users[e] : nu + items[e - batch];
    fB[r] = 1; f2[r] = 1;
  }
}

// single block, 1024 threads, scans up to 2048 block sums -> exclusive prefix
__device__ inline void scan_block_1024(const int* __restrict__ bsum, int nb,
                                       int* __restrict__ bpref,
                                       int* a, int* b) {
  int t = threadIdx.x;
  for (int i = t; i < 2048; i += 1024) a[i] = (i < nb) ? bsum[i] : 0;
  __syncthreads();
  int* cur = a; int* nxt = b;
  for (int off = 1; off < 2048; off <<= 1) {
    for (int i = t; i < 2048; i += 1024)
      nxt[i] = cur[i] + (i >= off ? cur[i - off] : 0);
    __syncthreads();
    int* tmp = cur; cur = nxt; nxt = tmp;
  }
  for (int i = t; i <= nb; i += 1024)
    bpref[i] = (i == 0) ? 0 : cur[i - 1];
  __syncthreads();
}

__global__ void k_scanb2x(const int* __restrict__ bA, int nA, int* __restrict__ pA,
                          const int* __restrict__ bB, int nB, int* __restrict__ pB) {
  __shared__ int a[2048], b[2048];
  scan_block_1024(bA, nA, pA, a, b);
  scan_block_1024(bB, nB, pB, a, b);
}

__global__ void k_scanb1(const int* __restrict__ bA, int nA, int* __restrict__ pA) {
  __shared__ int a[2048], b[2048];
  scan_block_1024(bA, nA, pA, a, b);
}

__global__ void k_blocksum(const int* __restrict__ cnt, int n, int* __restrict__ bsum) {
  __shared__ int s[256];
  int i = blockIdx.x * 256 + threadIdx.x;
  s[threadIdx.x] = (i < n) ? cnt[i] : 0;
  __syncthreads();
  for (int off = 128; off > 0; off >>= 1) {
    if (threadIdx.x < off) s[threadIdx.x] += s[threadIdx.x + off];
    __syncthreads();
  }
  if (threadIdx.x == 0) bsum[blockIdx.x] = s[0];
}

__global__ void k_scan_write(const int* __restrict__ cnt, int n, const int* __restrict__ bpref,
                             int* __restrict__ row_ptr, int* __restrict__ nextc) {
  __shared__ int a[256], b[256];
  int t = threadIdx.x;
  int i = blockIdx.x * 256 + t;
  int v = (i < n) ? cnt[i] : 0;
  a[t] = v;
  __syncthreads();
  int* cur = a; int* nxt = b;
  for (int off = 1; off < 256; off <<= 1) {
    nxt[t] = cur[t] + (t >= off ? cur[t - off] : 0);
    __syncthreads();
    int* tmp = cur; cur = nxt; nxt = tmp;
  }
  int incl = cur[t] + bpref[blockIdx.x];
  int excl = incl - v;
  if (i < n) { row_ptr[i] = excl; nextc[i] = excl; }
  if (i == n - 1) row_ptr[n] = incl;
}

// ---- user-half compaction: coalesced writes (kept edges stay row-sorted),
//      row_ptr_u from boundaries of the sorted rows array. Deterministic. ----
__global__ __launch_bounds__(1024) void k_compactU(
    const int* __restrict__ rows, const int* __restrict__ cols,
    const float* __restrict__ avals, const unsigned long long* __restrict__ keepw,
    const int* __restrict__ bprefE, int E2, int nu, int nbE,
    int2* __restrict__ uslot, int* __restrict__ row_ptr_u) {
  __shared__ int a[1024], b[1024];
  int t = threadIdx.x;
  int e = blockIdx.x * 1024 + t;
  bool kept = (e < E2) && ((keepw[e >> 6] >> (e & 63)) & 1ull);
  a[t] = kept ? 1 : 0;
  __syncthreads();
  int* cur = a; int* nxt = b;
  for (int off = 1; off < 1024; off <<= 1) {
    nxt[t] = cur[t] + (t >= off ? cur[t - off] : 0);
    __syncthreads();
    int* tmp = cur; cur = nxt; nxt = tmp;
  }
  int excl = cur[t] - (kept ? 1 : 0);
  int pos = bprefE[blockIdx.x] + excl;
  if (kept) uslot[pos] = make_int2(cols[e], __float_as_int(avals[e] * 2.0f));
  if (e < E2) {
    int r = rows[e];
    int rp = (e == 0) ? -1 : rows[e - 1];
    for (int rr = rp + 1; rr <= r; ++rr) row_ptr_u[rr] = pos;
    if (e == E2 - 1) {
      int total = bprefE[nbE];
      for (int rr = r + 1; rr <= nu; ++rr) row_ptr_u[rr] = total;
    }
  }
}

// ---- item-half scatter (small: ~kept/2 random 8B writes into ~4MB) ----
__global__ void k_scatterI(const int* __restrict__ rows, const int* __restrict__ cols,
                           const float* __restrict__ avals,
                           const unsigned long long* __restrict__ keepw,
                           int E, int E2, int nu, int* __restrict__ nextc,
                           int2* __restrict__ islot) {
  int e = E2 + blockIdx.x * 256 + threadIdx.x;
  if (e >= E) return;
  if (!((keepw[e >> 6] >> (e & 63)) & 1ull)) return;
  int r = rows[e] - nu;
  int k = atomicAdd(&nextc[r], 1);
  islot[k] = make_int2(cols[e], __float_as_int(avals[e] * 2.0f));
}

// ---------------- frontier: f2 = batch u N(batch) ----------------
__global__ void k_mark_neighbors(const uint8_t* __restrict__ fin,
                                 const int* __restrict__ row_ptr_u,
                                 const int2* __restrict__ uslot,
                                 const int* __restrict__ row_ptr_i,
                                 const int2* __restrict__ islot,
                                 int n, int nu, uint8_t* __restrict__ fout) {
  int r = blockIdx.x * 256 + threadIdx.x;
  if (r >= n) return;
  if (!fin[r]) return;
  const int* rp = (r < nu) ? row_ptr_u : row_ptr_i;
  const int2* sl = (r < nu) ? uslot : islot;
  int rr = (r < nu) ? r : r - nu;
  int s = rp[rr], e = rp[rr + 1];
  for (int k = s; k < e; ++k) fout[sl[k].x] = 1;
}

__global__ void k_flagsum1(const uint8_t* __restrict__ f, int n, int* __restrict__ bsum) {
  __shared__ int s1[256];
  int i = blockIdx.x * 256 + threadIdx.x;
  s1[threadIdx.x] = (i < n) ? (int)f[i] : 0;
  __syncthreads();
  for (int off = 128; off > 0; off >>= 1) {
    if (threadIdx.x < off) s1[threadIdx.x] += s1[threadIdx.x + off];
    __syncthreads();
  }
  if (threadIdx.x == 0) bsum[blockIdx.x] = s1[0];
}

__global__ void k_compact1(const uint8_t* __restrict__ f, int n,
                           const int* __restrict__ bpref, int* __restrict__ list) {
  __shared__ int a[256], b[256];
  int t = threadIdx.x;
  int i = blockIdx.x * 256 + t;
  int v = (i < n) ? (int)f[i] : 0;
  a[t] = v;
  __syncthreads();
  int* cur = a; int* nxt = b;
  for (int off = 1; off < 256; off <<= 1) {
    nxt[t] = cur[t] + (t >= off ? cur[t - off] : 0);
    __syncthreads();
    int* tmp = cur; cur = nxt; nxt = tmp;
  }
  if (v) list[bpref[blockIdx.x] + cur[t] - 1] = i;
}

// -------- SPMM over ALL rows: 8 lanes/row, 4-edge unroll, bf16 in/out ------
__global__ __launch_bounds__(256) void k_spmm_all(
    const int* __restrict__ row_ptr_u, const int2* __restrict__ uslot,
    const int* __restrict__ row_ptr_i, const int2* __restrict__ islot,
    const uint32_t* __restrict__ xin, uint32_t* __restrict__ xout,
    int nn, int nu) {
  int r = blockIdx.x * 32 + (threadIdx.x >> 3);
  if (r >= nn) return;
  int j = threadIdx.x & 7;
  bool isu = r < nu;
  const int* rp = isu ? row_ptr_u : row_ptr_i;
  const int2* sl = isu ? uslot : islot;
  int rr = isu ? r : r - nu;
  int s = rp[rr], e = rp[rr + 1];
  float a[8] = {0, 0, 0, 0, 0, 0, 0, 0};
  int last = e - 1;
  for (int k = s; k < e; k += 4) {
    int i1 = (k + 1 <= last) ? k + 1 : last;
    int i2 = (k + 2 <= last) ? k + 2 : last;
    int i3 = (k + 3 <= last) ? k + 3 : last;
    int2 s0 = sl[k], s1 = sl[i1], s2 = sl[i2], s3 = sl[i3];
    float v0 = __int_as_float(s0.y);
    float v1 = (k + 1 <= last) ? __int_as_float(s1.y) : 0.0f;
    float v2 = (k + 2 <= last) ? __int_as_float(s2.y) : 0.0f;
    float v3 = (k + 3 <= last) ? __int_as_float(s3.y) : 0.0f;
    uint4 u0 = *(const uint4*)(xin + (size_t)s0.x * 32 + 4 * j);
    uint4 u1 = *(const uint4*)(xin + (size_t)s1.x * 32 + 4 * j);
    uint4 u2 = *(const uint4*)(xin + (size_t)s2.x * 32 + 4 * j);
    uint4 u3 = *(const uint4*)(xin + (size_t)s3.x * 32 + 4 * j);
    fma8_bf(a, v0, u0);
    fma8_bf(a, v1, u1);
    fma8_bf(a, v2, u2);
    fma8_bf(a, v3, u3);
  }
  uint4 o;
  o.x = bf_pack(a[0], a[1]); o.y = bf_pack(a[2], a[3]);
  o.z = bf_pack(a[4], a[5]); o.w = bf_pack(a[6], a[7]);
  *(uint4*)(xout + (size_t)r * 32 + 4 * j) = o;
}

// -------- SPMM over a row list (layer 2: f2 rows only) --------
__global__ __launch_bounds__(256) void k_spmm(
    const int* __restrict__ row_ptr_u, const int2* __restrict__ uslot,
    const int* __restrict__ row_ptr_i, const int2* __restrict__ islot,
    const uint32_t* __restrict__ xin, uint32_t* __restrict__ xout,
    const int* __restrict__ rowlist, const int* __restrict__ nrows_p, int nu) {
  int nrows = *nrows_p;
  int i = blockIdx.x * 32 + (threadIdx.x >> 3);
  if (i >= nrows) return;
  int r = rowlist[i];
  int j = threadIdx.x & 7;
  bool isu = r < nu;
  const int* rp = isu ? row_ptr_u : row_ptr_i;
  const int2* sl = isu ? uslot : islot;
  int rr = isu ? r : r - nu;
  int s = rp[rr], e = rp[rr + 1];
  float a[8] = {0, 0, 0, 0, 0, 0, 0, 0};
  int last = e - 1;
  for (int k = s; k < e; k += 4) {
    int i1 = (k + 1 <= last) ? k + 1 : last;
    int i2 = (k + 2 <= last) ? k + 2 : last;
    int i3 = (k + 3 <= last) ? k + 3 : last;
    int2 s0 = sl[k], s1 = sl[i1], s2 = sl[i2], s3 = sl[i3];
    float v0 = __int_as_float(s0.y);
    float v1 = (k + 1 <= last) ? __int_as_float(s1.y) : 0.0f;
    float v2 = (k + 2 <= last) ? __int_as_float(s2.y) : 0.0f;
    float v3 = (k + 3 <= last) ? __int_as_float(s3.y) : 0.0f;
    uint4 u0 = *(const uint4*)(xin + (size_t)s0.x * 32 + 4 * j);
    uint4 u1 = *(const uint4*)(xin + (size_t)s1.x * 32 + 4 * j);
    uint4 u2 = *(const uint4*)(xin + (size_t)s2.x * 32 + 4 * j);
    uint4 u3 = *(const uint4*)(xin + (size_t)s3.x * 32 + 4 * j);
    fma8_bf(a, v0, u0);
    fma8_bf(a, v1, u1);
    fma8_bf(a, v2, u2);
    fma8_bf(a, v3, u3);
  }
  uint4 o;
  o.x = bf_pack(a[0], a[1]); o.y = bf_pack(a[2], a[3]);
  o.z = bf_pack(a[4], a[5]); o.w = bf_pack(a[6], a[7]);
  *(uint4*)(xout + (size_t)r * 32 + 4 * j) = o;
}

// ---- tail: out = ((emb + X0) + X1 + A*X1) / 4, plus target masks.
//      Single pure-write pass over out (gatherA fused in, same FP order). ----
__global__ __launch_bounds__(256) void k_tail(
    const int* __restrict__ row_ptr_u, const int2* __restrict__ uslot,
    const int* __restrict__ row_ptr_i, const int2* __restrict__ islot,
    const uint32_t* __restrict__ x0, const uint32_t* __restrict__ x1,
    const float* __restrict__ uemb, const float* __restrict__ iemb,
    const int* __restrict__ users, const int* __restrict__ items,
    float* __restrict__ out, int batch, int nu,
    uint32_t ku0, uint32_t ku1, uint32_t ki0, uint32_t ki1) {
  int b = blockIdx.x * 32 + (threadIdx.x >> 3);
  if (b >= 2 * batch) return;
  int j = threadIdx.x & 7;
  size_t H = (size_t)batch * 64;
  const int* rp; const int2* sl; int rr; size_t dst; int f0; uint32_t mk0, mk1;
  bool isu = b < batch;
  if (isu) {
    rr = users[b];
    rp = row_ptr_u; sl = uslot;
    dst = (size_t)b * 64 + 8 * j;
    f0 = b * 64 + 8 * j;
    mk0 = ku0; mk1 = ku1;
  } else {
    int bi = b - batch;
    rr = items[bi];
    rp = row_ptr_i; sl = islot;
    dst = 2 * H + (size_t)bi * 64 + 8 * j;
    f0 = bi * 64 + 8 * j;
    mk0 = ki0; mk1 = ki1;
  }
  // layer-3 accumulation from X1 over this row's edges
  int s = rp[rr], e = rp[rr + 1];
  float a[8] = {0, 0, 0, 0, 0, 0, 0, 0};
  int last = e - 1;
  for (int k = s; k < e; k += 4) {
    int i1 = (k + 1 <= last) ? k + 1 : last;
    int i2 = (k + 2 <= last) ? k + 2 : last;
    int i3 = (k + 3 <= last) ? k + 3 : last;
    int2 s0 = sl[k], s1 = sl[i1], s2 = sl[i2], s3 = sl[i3];
    float v0 = __int_as_float(s0.y);
    float v1 = (k + 1 <= last) ? __int_as_float(s1.y) : 0.0f;
    float v2 = (k + 2 <= last) ? __int_as_float(s2.y) : 0.0f;
    float v3 = (k + 3 <= last) ? __int_as_float(s3.y) : 0.0f;
    uint4 u0 = *(const uint4*)(x1 + (size_t)s0.x * 32 + 4 * j);
    uint4 u1 = *(const uint4*)(x1 + (size_t)s1.x * 32 + 4 * j);
    uint4 u2 = *(const uint4*)(x1 + (size_t)s2.x * 32 + 4 * j);
    uint4 u3 = *(const uint4*)(x1 + (size_t)s3.x * 32 + 4 * j);
    fma8_bf(a, v0, u0);
    fma8_bf(a, v1, u1);
    fma8_bf(a, v2, u2);
    fma8_bf(a, v3, u3);
  }
  // layer 0: fp32 embedding
  const float* pe = (isu ? uemb + (size_t)rr * 64 : iemb + (size_t)rr * 64) + 8 * j;
  float4 t0 = *(const float4*)pe;
  float4 t1 = *(const float4*)(pe + 4);
  int xr = isu ? rr : nu + rr;
  // + layer 1 (X0), then + layer 2 (X1), then + layer 3 (a) — same order as before
  uint4 u0r = *(const uint4*)(x0 + (size_t)xr * 32 + 4 * j);
  t0.x += bf_lo(u0r.x); t0.y += bf_hi(u0r.x); t0.z += bf_lo(u0r.y); t0.w += bf_hi(u0r.y);
  t1.x += bf_lo(u0r.z); t1.y += bf_hi(u0r.z); t1.z += bf_lo(u0r.w); t1.w += bf_hi(u0r.w);
  uint4 u1r = *(const uint4*)(x1 + (size_t)xr * 32 + 4 * j);
  t0.x += bf_lo(u1r.x); t0.y += bf_hi(u1r.x); t0.z += bf_lo(u1r.y); t0.w += bf_hi(u1r.y);
  t1.x += bf_lo(u1r.z); t1.y += bf_hi(u1r.z); t1.z += bf_lo(u1r.w); t1.w += bf_hi(u1r.w);
  t0.x += a[0]; t0.y += a[1]; t0.z += a[2]; t0.w += a[3];
  t1.x += a[4]; t1.y += a[5]; t1.z += a[6]; t1.w += a[7];
  float ov[8] = {t0.x * 0.25f, t0.y * 0.25f, t0.z * 0.25f, t0.w * 0.25f,
                 t1.x * 0.25f, t1.y * 0.25f, t1.z * 0.25f, t1.w * 0.25f};
  float tv[8];
#pragma unroll
  for (int c = 0; c < 8; ++c) {
    bool present = (bits32(mk0, mk1, (uint32_t)(f0 + c)) >> 31) == 0u;
    tv[c] = present ? ov[c] * 2.0f : 0.0f;
  }
  float* o = out + dst;
  *(float4*)o = make_float4(ov[0], ov[1], ov[2], ov[3]);
  *(float4*)(o + 4) = make_float4(ov[4], ov[5], ov[6], ov[7]);
  *(float4*)(o + H) = make_float4(tv[0], tv[1], tv[2], tv[3]);
  *(float4*)(o + H + 4) = make_float4(tv[4], tv[5], tv[6], tv[7]);
}

extern "C" void kernel_launch(void* const* d_in, const int* in_sizes, int n_in,
                              void* d_out, int out_size, void* d_ws, size_t ws_size,
                              hipStream_t stream) {
  const float* uemb  = (const float*)d_in[0];
  const float* iemb  = (const float*)d_in[1];
  const float* avals = (const float*)d_in[2];
  const int*   rows  = (const int*)d_in[3];
  const int*   cols  = (const int*)d_in[4];
  const int*   users = (const int*)d_in[5];
  const int*   items = (const int*)d_in[6];
  const int DIM = 64;
  const int NU = in_sizes[0] / DIM;
  const int NI = in_sizes[1] / DIM;
  const int E  = in_sizes[2];
  const int E2 = E / 2;             // first half: user rows, sorted by row
  const int B = in_sizes[5];
  const int NN = NU + NI;
  float* out = (float*)d_out;
  (void)n_in; (void)out_size; (void)ws_size;

  // derived subkeys: split(key(1234), 3) fold-like = threefry(key, (0, i))
  uint32_t ke0, ke1, ku0, ku1, ki0, ki1;
  tf2x32(0u, 1234u, 0u, 0u, ke0, ke1);
  tf2x32(0u, 1234u, 0u, 1u, ku0, ku1);
  tf2x32(0u, 1234u, 0u, 2u, ki0, ki1);

  // workspace carve
  char* p = (char*)d_ws;
  auto carve = [&](size_t bytes) {
    char* r = p;
    p += (bytes + 255) & ~(size_t)255;
    return (void*)r;
  };
  uint32_t* Xe    = (uint32_t*)carve((size_t)NN * 32 * 4);  // bf16 embeddings
  uint32_t* X0    = (uint32_t*)carve((size_t)NN * 32 * 4);  // layer-1 result
  uint32_t* X1    = (uint32_t*)carve((size_t)NN * 32 * 4);  // layer-2 result
  int2*  uslot    = (int2*)carve((size_t)E2 * 8);
  int2*  islot    = (int2*)carve((size_t)(E - E2) * 8);
  unsigned long long* keepw = (unsigned long long*)carve(((size_t)E / 64 + 2) * 8);
  int*   cnt      = (int*)carve((size_t)NI * 4);
  int*   row_ptr_u = (int*)carve((size_t)(NU + 1) * 4);
  int*   row_ptr_i = (int*)carve((size_t)(NI + 1) * 4);
  int*   nextc    = (int*)carve((size_t)NI * 4);
  uint8_t* fB     = (uint8_t*)carve((size_t)NN * 2);  // fB | f2
  uint8_t* f2     = fB + NN;
  int*   list2    = (int*)carve((size_t)NN * 4);
  const int GK    = (E + 1023) / 1024;
  const int NBE   = (E2 + 1023) / 1024;
  const int NBI   = (NI + 255) / 256;
  const int NB    = (NN + 255) / 256;
  int*   bsumE    = (int*)carve((size_t)GK * 4);
  int*   bprefE   = (int*)carve((size_t)(NBE + 1) * 4);
  int*   bsumI    = (int*)carve((size_t)NBI * 4);
  int*   bprefI   = (int*)carve((size_t)(NBI + 1) * 4);
  int*   bsum2    = (int*)carve((size_t)NB * 4);
  int*   bpref2   = (int*)carve((size_t)(NB + 1) * 4);   // bpref2[NB] = |list2|

  // init: clear cnt + flags, convert embeddings to bf16 — one dispatch
  {
    const int fw = (int)(((size_t)NN * 2 + 3) / 4);
    const int gI = (NI + fw + NN * 8 + 255) / 256;
    k_init<<<gI, 256, 0, stream>>>(cnt, NI, (uint32_t*)fB, fw, uemb, iemb, Xe, NU, NN);
  }

  // CSR build + batch marking
  k_keep<<<GK, 1024, 0, stream>>>(rows, E, E2, NU, keepw, bsumE, cnt,
                                  users, items, B, fB, f2, ke0, ke1);
  k_blocksum<<<NBI, 256, 0, stream>>>(cnt, NI, bsumI);
  k_scanb2x<<<1, 1024, 0, stream>>>(bsumE, NBE, bprefE, bsumI, NBI, bprefI);
  k_scan_write<<<NBI, 256, 0, stream>>>(cnt, NI, bprefI, row_ptr_i, nextc);
  k_compactU<<<NBE, 1024, 0, stream>>>(rows, cols, avals, keepw, bprefE, E2, NU, NBE,
                                       uslot, row_ptr_u);
  {
    const int gI = (E - E2 + 255) / 256;
    k_scatterI<<<gI, 256, 0, stream>>>(rows, cols, avals, keepw, E, E2, NU, nextc, islot);
  }

  // frontier f2 = batch u N(batch) -> list2
  const int gN = (NN + 255) / 256;
  k_mark_neighbors<<<gN, 256, 0, stream>>>(fB, row_ptr_u, uslot, row_ptr_i, islot, NN, NU, f2);
  k_flagsum1<<<NB, 256, 0, stream>>>(f2, NN, bsum2);
  k_scanb1<<<1, 1024, 0, stream>>>(bsum2, NB, bpref2);
  k_compact1<<<NB, 256, 0, stream>>>(f2, NN, bpref2, list2);

  const int gG = (2 * B + 31) / 32;
  const int gS = (NN + 31) / 32;

  // layer 1: X0 = A * bf16(emb), ALL rows (no frontier)
  k_spmm_all<<<gS, 256, 0, stream>>>(row_ptr_u, uslot, row_ptr_i, islot, Xe, X0, NN, NU);
  // layer 2: X1 = A * X0, f2 rows only
  k_spmm<<<gS, 256, 0, stream>>>(row_ptr_u, uslot, row_ptr_i, islot, X0, X1,
                                 list2, bpref2 + NB, NU);
  // tail: out = ((emb + X0) + X1 + A*X1)/4 + target masks, single write pass
  k_tail<<<gG, 256, 0, stream>>>(row_ptr_u, uslot, row_ptr_i, islot, X0, X1,
                                 uemb, iemb, users, items, out, B, NU,
                                 ku0, ku1, ki0, ki1);
}

// Round 13
// 155.878 us; speedup vs baseline: 1.1084x; 1.0071x over previous
//
#include <hip/hip_runtime.h>
#include <stdint.h>

// ---------------- JAX threefry2x32 (partitionable mode) ----------------
__host__ __device__ inline void tf2x32(uint32_t k0, uint32_t k1,
                                       uint32_t x0, uint32_t x1,
                                       uint32_t& o0, uint32_t& o1) {
  const uint32_t ks2 = k0 ^ k1 ^ 0x1BD11BDAu;
  x0 += k0; x1 += k1;
#define TFR(r) { x0 += x1; x1 = (x1 << (r)) | (x1 >> (32 - (r))); x1 ^= x0; }
  TFR(13) TFR(15) TFR(26) TFR(6)
  x0 += k1;  x1 += ks2 + 1u;
  TFR(17) TFR(29) TFR(16) TFR(24)
  x0 += ks2; x1 += k0 + 2u;
  TFR(13) TFR(15) TFR(26) TFR(6)
  x0 += k0;  x1 += k1 + 3u;
  TFR(17) TFR(29) TFR(16) TFR(24)
  x0 += k1;  x1 += ks2 + 4u;
  TFR(13) TFR(15) TFR(26) TFR(6)
  x0 += ks2; x1 += k0 + 5u;
#undef TFR
  o0 = x0; o1 = x1;
}

__host__ __device__ inline uint32_t bits32(uint32_t k0, uint32_t k1, uint32_t idx) {
  uint32_t a, b;
  tf2x32(k0, k1, 0u, idx, a, b);
  return a ^ b;
}

// keep-edge iff uniform >= 0.5 iff bit31 of bits set (floor(0.5+u) == 1)
__device__ inline bool edge_kept(uint32_t k0, uint32_t k1, uint32_t e) {
  return (bits32(k0, k1, e) >> 31) != 0u;
}

__device__ inline float bf_lo(uint32_t u) { return __uint_as_float(u << 16); }
__device__ inline float bf_hi(uint32_t u) { return __uint_as_float(u & 0xffff0000u); }
__device__ inline uint32_t bf_pack(float a, float b) {
  uint32_t lo = (__float_as_uint(a) + 0x8000u) >> 16;
  uint32_t hi = (__float_as_uint(b) + 0x8000u) & 0xffff0000u;
  return hi | lo;
}

__device__ inline void fma8_bf(float a[8], float v, const uint4& u) {
  a[0] = fmaf(v, bf_lo(u.x), a[0]); a[1] = fmaf(v, bf_hi(u.x), a[1]);
  a[2] = fmaf(v, bf_lo(u.y), a[2]); a[3] = fmaf(v, bf_hi(u.y), a[3]);
  a[4] = fmaf(v, bf_lo(u.z), a[4]); a[5] = fmaf(v, bf_hi(u.z), a[5]);
  a[6] = fmaf(v, bf_lo(u.w), a[6]); a[7] = fmaf(v, bf_hi(u.w), a[7]);
}

// -------- init: clear cnt + flags, and emb->bf16x2 stream, one dispatch ----
__global__ void k_init(int* __restrict__ cnt, int ni,
                       uint32_t* __restrict__ flagw, int fw,
                       const float* __restrict__ uemb, const float* __restrict__ iemb,
                       uint32_t* __restrict__ xe, int nu, int nn) {
  int i = blockIdx.x * 256 + threadIdx.x;
  if (i < ni) { cnt[i] = 0; return; }
  i -= ni;
  if (i < fw) { flagw[i] = 0; return; }
  i -= fw;
  if (i >= nn * 8) return;
  int r = i >> 3, q = i & 7;
  const float* p = (r < nu) ? uemb + (size_t)r * 64 : iemb + (size_t)(r - nu) * 64;
  float4 f0 = *(const float4*)(p + 8 * q);
  float4 f1 = *(const float4*)(p + 8 * q + 4);
  uint4 o;
  o.x = bf_pack(f0.x, f0.y); o.y = bf_pack(f0.z, f0.w);
  o.z = bf_pack(f1.x, f1.y); o.w = bf_pack(f1.z, f1.w);
  *(uint4*)(xe + (size_t)r * 32 + 4 * q) = o;
}

// ---------------- keep bits + first-half block sums + item counts +
//                  batch marking, one pass ----------------
__global__ __launch_bounds__(1024) void k_keep(
    const int* __restrict__ rows, int E, int E2, int nu,
    unsigned long long* __restrict__ keepw, int* __restrict__ bsumE,
    int* __restrict__ cnt, const int* __restrict__ users,
    const int* __restrict__ items, int batch,
    uint8_t* __restrict__ fB, uint8_t* __restrict__ f2,
    uint32_t ke0, uint32_t ke1) {
  __shared__ int s[16];
  int e = blockIdx.x * 1024 + threadIdx.x;
  int lane = threadIdx.x & 63;
  int wid = threadIdx.x >> 6;
  bool kept = (e < E) && edge_kept(ke0, ke1, (uint32_t)e);
  unsigned long long m = __ballot(kept);
  int ws = blockIdx.x * 1024 + wid * 64;
  if (lane == 0 && ws < E) keepw[ws >> 6] = m;
  int nf = 0;
  if (ws + 64 <= E2) nf = __popcll(m);
  else if (ws < E2) nf = __popcll(m & ((1ull << (E2 - ws)) - 1ull));
  if (lane == 0) s[wid] = nf;
  __syncthreads();
  if (threadIdx.x == 0) {
    int t = 0;
    for (int i = 0; i < 16; ++i) t += s[i];
    bsumE[blockIdx.x] = t;
  }
  if (kept && e >= E2) atomicAdd(&cnt[rows[e] - nu], 1);
  // batch marking (first blocks cover 2*batch)
  if (e < 2 * batch) {
    int r = (e < batch) ? users[e] : nu + items[e - batch];
    fB[r] = 1; f2[r] = 1;
  }
}

// single block, 1024 threads, scans up to 2048 block sums -> exclusive prefix
__device__ inline void scan_block_1024(const int* __restrict__ bsum, int nb,
                                       int* __restrict__ bpref,
                                       int* a, int* b) {
  int t = threadIdx.x;
  for (int i = t; i < 2048; i += 1024) a[i] = (i < nb) ? bsum[i] : 0;
  __syncthreads();
  int* cur = a; int* nxt = b;
  for (int off = 1; off < 2048; off <<= 1) {
    for (int i = t; i < 2048; i += 1024)
      nxt[i] = cur[i] + (i >= off ? cur[i - off] : 0);
    __syncthreads();
    int* tmp = cur; cur = nxt; nxt = tmp;
  }
  for (int i = t; i <= nb; i += 1024)
    bpref[i] = (i == 0) ? 0 : cur[i - 1];
  __syncthreads();
}

__global__ void k_scanb2x(const int* __restrict__ bA, int nA, int* __restrict__ pA,
                          const int* __restrict__ bB, int nB, int* __restrict__ pB) {
  __shared__ int a[2048], b[2048];
  scan_block_1024(bA, nA, pA, a, b);
  scan_block_1024(bB, nB, pB, a, b);
}

__global__ void k_scanb1(const int* __restrict__ bA, int nA, int* __restrict__ pA) {
  __shared__ int a[2048], b[2048];
  scan_block_1024(bA, nA, pA, a, b);
}

__global__ void k_blocksum(const int* __restrict__ cnt, int n, int* __restrict__ bsum) {
  __shared__ int s[256];
  int i = blockIdx.x * 256 + threadIdx.x;
  s[threadIdx.x] = (i < n) ? cnt[i] : 0;
  __syncthreads();
  for (int off = 128; off > 0; off >>= 1) {
    if (threadIdx.x < off) s[threadIdx.x] += s[threadIdx.x + off];
    __syncthreads();
  }
  if (threadIdx.x == 0) bsum[blockIdx.x] = s[0];
}

__global__ void k_scan_write(const int* __restrict__ cnt, int n, const int* __restrict__ bpref,
                             int* __restrict__ row_ptr, int* __restrict__ nextc) {
  __shared__ int a[256], b[256];
  int t = threadIdx.x;
  int i = blockIdx.x * 256 + t;
  int v = (i < n) ? cnt[i] : 0;
  a[t] = v;
  __syncthreads();
  int* cur = a; int* nxt = b;
  for (int off = 1; off < 256; off <<= 1) {
    nxt[t] = cur[t] + (t >= off ? cur[t - off] : 0);
    __syncthreads();
    int* tmp = cur; cur = nxt; nxt = tmp;
  }
  int incl = cur[t] + bpref[blockIdx.x];
  int excl = incl - v;
  if (i < n) { row_ptr[i] = excl; nextc[i] = excl; }
  if (i == n - 1) row_ptr[n] = incl;
}

// ---- user-half compaction: coalesced writes (kept edges stay row-sorted),
//      row_ptr_u from boundaries of the sorted rows array. Deterministic. ----
__global__ __launch_bounds__(1024) void k_compactU(
    const int* __restrict__ rows, const int* __restrict__ cols,
    const float* __restrict__ avals, const unsigned long long* __restrict__ keepw,
    const int* __restrict__ bprefE, int E2, int nu, int nbE,
    int2* __restrict__ uslot, int* __restrict__ row_ptr_u) {
  __shared__ int a[1024], b[1024];
  int t = threadIdx.x;
  int e = blockIdx.x * 1024 + t;
  bool kept = (e < E2) && ((keepw[e >> 6] >> (e & 63)) & 1ull);
  a[t] = kept ? 1 : 0;
  __syncthreads();
  int* cur = a; int* nxt = b;
  for (int off = 1; off < 1024; off <<= 1) {
    nxt[t] = cur[t] + (t >= off ? cur[t - off] : 0);
    __syncthreads();
    int* tmp = cur; cur = nxt; nxt = tmp;
  }
  int excl = cur[t] - (kept ? 1 : 0);
  int pos = bprefE[blockIdx.x] + excl;
  if (kept) uslot[pos] = make_int2(cols[e], __float_as_int(avals[e] * 2.0f));
  if (e < E2) {
    int r = rows[e];
    int rp = (e == 0) ? -1 : rows[e - 1];
    for (int rr = rp + 1; rr <= r; ++rr) row_ptr_u[rr] = pos;
    if (e == E2 - 1) {
      int total = bprefE[nbE];
      for (int rr = r + 1; rr <= nu; ++rr) row_ptr_u[rr] = total;
    }
  }
}

// ---- item-half scatter (small: ~kept/2 random 8B writes into ~4MB) ----
__global__ void k_scatterI(const int* __restrict__ rows, const int* __restrict__ cols,
                           const float* __restrict__ avals,
                           const unsigned long long* __restrict__ keepw,
                           int E, int E2, int nu, int* __restrict__ nextc,
                           int2* __restrict__ islot) {
  int e = E2 + blockIdx.x * 256 + threadIdx.x;
  if (e >= E) return;
  if (!((keepw[e >> 6] >> (e & 63)) & 1ull)) return;
  int r = rows[e] - nu;
  int k = atomicAdd(&nextc[r], 1);
  islot[k] = make_int2(cols[e], __float_as_int(avals[e] * 2.0f));
}

// ---------------- frontier: f2 = batch u N(batch) ----------------
__global__ void k_mark_neighbors(const uint8_t* __restrict__ fin,
                                 const int* __restrict__ row_ptr_u,
                                 const int2* __restrict__ uslot,
                                 const int* __restrict__ row_ptr_i,
                                 const int2* __restrict__ islot,
                                 int n, int nu, uint8_t* __restrict__ fout) {
  int r = blockIdx.x * 256 + threadIdx.x;
  if (r >= n) return;
  if (!fin[r]) return;
  const int* rp = (r < nu) ? row_ptr_u : row_ptr_i;
  const int2* sl = (r < nu) ? uslot : islot;
  int rr = (r < nu) ? r : r - nu;
  int s = rp[rr], e = rp[rr + 1];
  for (int k = s; k < e; ++k) fout[sl[k].x] = 1;
}

__global__ void k_flagsum1(const uint8_t* __restrict__ f, int n, int* __restrict__ bsum) {
  __shared__ int s1[256];
  int i = blockIdx.x * 256 + threadIdx.x;
  s1[threadIdx.x] = (i < n) ? (int)f[i] : 0;
  __syncthreads();
  for (int off = 128; off > 0; off >>= 1) {
    if (threadIdx.x < off) s1[threadIdx.x] += s1[threadIdx.x + off];
    __syncthreads();
  }
  if (threadIdx.x == 0) bsum[blockIdx.x] = s1[0];
}

__global__ void k_compact1(const uint8_t* __restrict__ f, int n,
                           const int* __restrict__ bpref, int* __restrict__ list) {
  __shared__ int a[256], b[256];
  int t = threadIdx.x;
  int i = blockIdx.x * 256 + t;
  int v = (i < n) ? (int)f[i] : 0;
  a[t] = v;
  __syncthreads();
  int* cur = a; int* nxt = b;
  for (int off = 1; off < 256; off <<= 1) {
    nxt[t] = cur[t] + (t >= off ? cur[t - off] : 0);
    __syncthreads();
    int* tmp = cur; cur = nxt; nxt = tmp;
  }
  if (v) list[bpref[blockIdx.x] + cur[t] - 1] = i;
}

// -------- SPMM over ALL rows: 8 lanes/row, 4-edge unroll, bf16 in/out ------
__global__ __launch_bounds__(256) void k_spmm_all(
    const int* __restrict__ row_ptr_u, const int2* __restrict__ uslot,
    const int* __restrict__ row_ptr_i, const int2* __restrict__ islot,
    const uint32_t* __restrict__ xin, uint32_t* __restrict__ xout,
    int nn, int nu) {
  int r = blockIdx.x * 32 + (threadIdx.x >> 3);
  if (r >= nn) return;
  int j = threadIdx.x & 7;
  bool isu = r < nu;
  const int* rp = isu ? row_ptr_u : row_ptr_i;
  const int2* sl = isu ? uslot : islot;
  int rr = isu ? r : r - nu;
  int s = rp[rr], e = rp[rr + 1];
  float a[8] = {0, 0, 0, 0, 0, 0, 0, 0};
  int last = e - 1;
  for (int k = s; k < e; k += 4) {
    int i1 = (k + 1 <= last) ? k + 1 : last;
    int i2 = (k + 2 <= last) ? k + 2 : last;
    int i3 = (k + 3 <= last) ? k + 3 : last;
    int2 s0 = sl[k], s1 = sl[i1], s2 = sl[i2], s3 = sl[i3];
    float v0 = __int_as_float(s0.y);
    float v1 = (k + 1 <= last) ? __int_as_float(s1.y) : 0.0f;
    float v2 = (k + 2 <= last) ? __int_as_float(s2.y) : 0.0f;
    float v3 = (k + 3 <= last) ? __int_as_float(s3.y) : 0.0f;
    uint4 u0 = *(const uint4*)(xin + (size_t)s0.x * 32 + 4 * j);
    uint4 u1 = *(const uint4*)(xin + (size_t)s1.x * 32 + 4 * j);
    uint4 u2 = *(const uint4*)(xin + (size_t)s2.x * 32 + 4 * j);
    uint4 u3 = *(const uint4*)(xin + (size_t)s3.x * 32 + 4 * j);
    fma8_bf(a, v0, u0);
    fma8_bf(a, v1, u1);
    fma8_bf(a, v2, u2);
    fma8_bf(a, v3, u3);
  }
  uint4 o;
  o.x = bf_pack(a[0], a[1]); o.y = bf_pack(a[2], a[3]);
  o.z = bf_pack(a[4], a[5]); o.w = bf_pack(a[6], a[7]);
  *(uint4*)(xout + (size_t)r * 32 + 4 * j) = o;
}

// -------- SPMM over a row list (layer 2: f2 rows only) --------
__global__ __launch_bounds__(256) void k_spmm(
    const int* __restrict__ row_ptr_u, const int2* __restrict__ uslot,
    const int* __restrict__ row_ptr_i, const int2* __restrict__ islot,
    const uint32_t* __restrict__ xin, uint32_t* __restrict__ xout,
    const int* __restrict__ rowlist, const int* __restrict__ nrows_p, int nu) {
  int nrows = *nrows_p;
  int i = blockIdx.x * 32 + (threadIdx.x >> 3);
  if (i >= nrows) return;
  int r = rowlist[i];
  int j = threadIdx.x & 7;
  bool isu = r < nu;
  const int* rp = isu ? row_ptr_u : row_ptr_i;
  const int2* sl = isu ? uslot : islot;
  int rr = isu ? r : r - nu;
  int s = rp[rr], e = rp[rr + 1];
  float a[8] = {0, 0, 0, 0, 0, 0, 0, 0};
  int last = e - 1;
  for (int k = s; k < e; k += 4) {
    int i1 = (k + 1 <= last) ? k + 1 : last;
    int i2 = (k + 2 <= last) ? k + 2 : last;
    int i3 = (k + 3 <= last) ? k + 3 : last;
    int2 s0 = sl[k], s1 = sl[i1], s2 = sl[i2], s3 = sl[i3];
    float v0 = __int_as_float(s0.y);
    float v1 = (k + 1 <= last) ? __int_as_float(s1.y) : 0.0f;
    float v2 = (k + 2 <= last) ? __int_as_float(s2.y) : 0.0f;
    float v3 = (k + 3 <= last) ? __int_as_float(s3.y) : 0.0f;
    uint4 u0 = *(const uint4*)(xin + (size_t)s0.x * 32 + 4 * j);
    uint4 u1 = *(const uint4*)(xin + (size_t)s1.x * 32 + 4 * j);
    uint4 u2 = *(const uint4*)(xin + (size_t)s2.x * 32 + 4 * j);
    uint4 u3 = *(const uint4*)(xin + (size_t)s3.x * 32 + 4 * j);
    fma8_bf(a, v0, u0);
    fma8_bf(a, v1, u1);
    fma8_bf(a, v2, u2);
    fma8_bf(a, v3, u3);
  }
  uint4 o;
  o.x = bf_pack(a[0], a[1]); o.y = bf_pack(a[2], a[3]);
  o.z = bf_pack(a[4], a[5]); o.w = bf_pack(a[6], a[7]);
  *(uint4*)(xout + (size_t)r * 32 + 4 * j) = o;
}

// ---- tail: out = ((emb + X0) + X1 + A*X1) / 4, plus target masks.
//      Single pure-write pass over out (gatherA fused in, same FP order). ----
__global__ __launch_bounds__(256) void k_tail(
    const int* __restrict__ row_ptr_u, const int2* __restrict__ uslot,
    const int* __restrict__ row_ptr_i, const int2* __restrict__ islot,
    const uint32_t* __restrict__ x0, const uint32_t* __restrict__ x1,
    const float* __restrict__ uemb, const float* __restrict__ iemb,
    const int* __restrict__ users, const int* __restrict__ items,
    float* __restrict__ out, int batch, int nu,
    uint32_t ku0, uint32_t ku1, uint32_t ki0, uint32_t ki1) {
  int b = blockIdx.x * 32 + (threadIdx.x >> 3);
  if (b >= 2 * batch) return;
  int j = threadIdx.x & 7;
  size_t H = (size_t)batch * 64;
  const int* rp; const int2* sl; int rr; size_t dst; int f0; uint32_t mk0, mk1;
  bool isu = b < batch;
  if (isu) {
    rr = users[b];
    rp = row_ptr_u; sl = uslot;
    dst = (size_t)b * 64 + 8 * j;
    f0 = b * 64 + 8 * j;
    mk0 = ku0; mk1 = ku1;
  } else {
    int bi = b - batch;
    rr = items[bi];
    rp = row_ptr_i; sl = islot;
    dst = 2 * H + (size_t)bi * 64 + 8 * j;
    f0 = bi * 64 + 8 * j;
    mk0 = ki0; mk1 = ki1;
  }
  // layer-3 accumulation from X1 over this row's edges
  int s = rp[rr], e = rp[rr + 1];
  float a[8] = {0, 0, 0, 0, 0, 0, 0, 0};
  int last = e - 1;
  for (int k = s; k < e; k += 4) {
    int i1 = (k + 1 <= last) ? k + 1 : last;
    int i2 = (k + 2 <= last) ? k + 2 : last;
    int i3 = (k + 3 <= last) ? k + 3 : last;
    int2 s0 = sl[k], s1 = sl[i1], s2 = sl[i2], s3 = sl[i3];
    float v0 = __int_as_float(s0.y);
    float v1 = (k + 1 <= last) ? __int_as_float(s1.y) : 0.0f;
    float v2 = (k + 2 <= last) ? __int_as_float(s2.y) : 0.0f;
    float v3 = (k + 3 <= last) ? __int_as_float(s3.y) : 0.0f;
    uint4 u0 = *(const uint4*)(x1 + (size_t)s0.x * 32 + 4 * j);
    uint4 u1 = *(const uint4*)(x1 + (size_t)s1.x * 32 + 4 * j);
    uint4 u2 = *(const uint4*)(x1 + (size_t)s2.x * 32 + 4 * j);
    uint4 u3 = *(const uint4*)(x1 + (size_t)s3.x * 32 + 4 * j);
    fma8_bf(a, v0, u0);
    fma8_bf(a, v1, u1);
    fma8_bf(a, v2, u2);
    fma8_bf(a, v3, u3);
  }
  // layer 0: fp32 embedding
  const float* pe = (isu ? uemb + (size_t)rr * 64 : iemb + (size_t)rr * 64) + 8 * j;
  float4 t0 = *(const float4*)pe;
  float4 t1 = *(const float4*)(pe + 4);
  int xr = isu ? rr : nu + rr;
  // + layer 1 (X0), then + layer 2 (X1), then + layer 3 (a) — same order as before
  uint4 u0r = *(const uint4*)(x0 + (size_t)xr * 32 + 4 * j);
  t0.x += bf_lo(u0r.x); t0.y += bf_hi(u0r.x); t0.z += bf_lo(u0r.y); t0.w += bf_hi(u0r.y);
  t1.x += bf_lo(u0r.z); t1.y += bf_hi(u0r.z); t1.z += bf_lo(u0r.w); t1.w += bf_hi(u0r.w);
  uint4 u1r = *(const uint4*)(x1 + (size_t)xr * 32 + 4 * j);
  t0.x += bf_lo(u1r.x); t0.y += bf_hi(u1r.x); t0.z += bf_lo(u1r.y); t0.w += bf_hi(u1r.y);
  t1.x += bf_lo(u1r.z); t1.y += bf_hi(u1r.z); t1.z += bf_lo(u1r.w); t1.w += bf_hi(u1r.w);
  t0.x += a[0]; t0.y += a[1]; t0.z += a[2]; t0.w += a[3];
  t1.x += a[4]; t1.y += a[5]; t1.z += a[6]; t1.w += a[7];
  float ov[8] = {t0.x * 0.25f, t0.y * 0.25f, t0.z * 0.25f, t0.w * 0.25f,
                 t1.x * 0.25f, t1.y * 0.25f, t1.z * 0.25f, t1.w * 0.25f};
  float tv[8];
#pragma unroll
  for (int c = 0; c < 8; ++c) {
    bool present = (bits32(mk0, mk1, (uint32_t)(f0 + c)) >> 31) == 0u;
    tv[c] = present ? ov[c] * 2.0f : 0.0f;
  }
  float* o = out + dst;
  *(float4*)o = make_float4(ov[0], ov[1], ov[2], ov[3]);
  *(float4*)(o + 4) = make_float4(ov[4], ov[5], ov[6], ov[7]);
  *(float4*)(o + H) = make_float4(tv[0], tv[1], tv[2], tv[3]);
  *(float4*)(o + H + 4) = make_float4(tv[4], tv[5], tv[6], tv[7]);
}

extern "C" void kernel_launch(void* const* d_in, const int* in_sizes, int n_in,
                              void* d_out, int out_size, void* d_ws, size_t ws_size,
                              hipStream_t stream) {
  const float* uemb  = (const float*)d_in[0];
  const float* iemb  = (const float*)d_in[1];
  const float* avals = (const float*)d_in[2];
  const int*   rows  = (const int*)d_in[3];
  const int*   cols  = (const int*)d_in[4];
  const int*   users = (const int*)d_in[5];
  const int*   items = (const int*)d_in[6];
  const int DIM = 64;
  const int NU = in_sizes[0] / DIM;
  const int NI = in_sizes[1] / DIM;
  const int E  = in_sizes[2];
  const int E2 = E / 2;             // first half: user rows, sorted by row
  const int B = in_sizes[5];
  const int NN = NU + NI;
  float* out = (float*)d_out;
  (void)n_in; (void)out_size; (void)ws_size;

  // derived subkeys: split(key(1234), 3) fold-like = threefry(key, (0, i))
  uint32_t ke0, ke1, ku0, ku1, ki0, ki1;
  tf2x32(0u, 1234u, 0u, 0u, ke0, ke1);
  tf2x32(0u, 1234u, 0u, 1u, ku0, ku1);
  tf2x32(0u, 1234u, 0u, 2u, ki0, ki1);

  // workspace carve
  char* p = (char*)d_ws;
  auto carve = [&](size_t bytes) {
    char* r = p;
    p += (bytes + 255) & ~(size_t)255;
    return (void*)r;
  };
  uint32_t* Xe    = (uint32_t*)carve((size_t)NN * 32 * 4);  // bf16 embeddings
  uint32_t* X0    = (uint32_t*)carve((size_t)NN * 32 * 4);  // layer-1 result
  uint32_t* X1    = (uint32_t*)carve((size_t)NN * 32 * 4);  // layer-2 result
  int2*  uslot    = (int2*)carve((size_t)E2 * 8);
  int2*  islot    = (int2*)carve((size_t)(E - E2) * 8);
  unsigned long long* keepw = (unsigned long long*)carve(((size_t)E / 64 + 2) * 8);
  int*   cnt      = (int*)carve((size_t)NI * 4);
  int*   row_ptr_u = (int*)carve((size_t)(NU + 1) * 4);
  int*   row_ptr_i = (int*)carve((size_t)(NI + 1) * 4);
  int*   nextc    = (int*)carve((size_t)NI * 4);
  uint8_t* fB     = (uint8_t*)carve((size_t)NN * 2);  // fB | f2
  uint8_t* f2     = fB + NN;
  int*   list2    = (int*)carve((size_t)NN * 4);
  const int GK    = (E + 1023) / 1024;
  const int NBE   = (E2 + 1023) / 1024;
  const int NBI   = (NI + 255) / 256;
  const int NB    = (NN + 255) / 256;
  int*   bsumE    = (int*)carve((size_t)GK * 4);
  int*   bprefE   = (int*)carve((size_t)(NBE + 1) * 4);
  int*   bsumI    = (int*)carve((size_t)NBI * 4);
  int*   bprefI   = (int*)carve((size_t)(NBI + 1) * 4);
  int*   bsum2    = (int*)carve((size_t)NB * 4);
  int*   bpref2   = (int*)carve((size_t)(NB + 1) * 4);   // bpref2[NB] = |list2|

  // init: clear cnt + flags, convert embeddings to bf16 — one dispatch
  {
    const int fw = (int)(((size_t)NN * 2 + 3) / 4);
    const int gI = (NI + fw + NN * 8 + 255) / 256;
    k_init<<<gI, 256, 0, stream>>>(cnt, NI, (uint32_t*)fB, fw, uemb, iemb, Xe, NU, NN);
  }

  // CSR build + batch marking
  k_keep<<<GK, 1024, 0, stream>>>(rows, E, E2, NU, keepw, bsumE, cnt,
                                  users, items, B, fB, f2, ke0, ke1);
  k_blocksum<<<NBI, 256, 0, stream>>>(cnt, NI, bsumI);
  k_scanb2x<<<1, 1024, 0, stream>>>(bsumE, NBE, bprefE, bsumI, NBI, bprefI);
  k_scan_write<<<NBI, 256, 0, stream>>>(cnt, NI, bprefI, row_ptr_i, nextc);
  k_compactU<<<NBE, 1024, 0, stream>>>(rows, cols, avals, keepw, bprefE, E2, NU, NBE,
                                       uslot, row_ptr_u);
  {
    const int gI = (E - E2 + 255) / 256;
    k_scatterI<<<gI, 256, 0, stream>>>(rows, cols, avals, keepw, E, E2, NU, nextc, islot);
  }

  // frontier f2 = batch u N(batch) -> list2
  const int gN = (NN + 255) / 256;
  k_mark_neighbors<<<gN, 256, 0, stream>>>(fB, row_ptr_u, uslot, row_ptr_i, islot, NN, NU, f2);
  k_flagsum1<<<NB, 256, 0, stream>>>(f2, NN, bsum2);
  k_scanb1<<<1, 1024, 0, stream>>>(bsum2, NB, bpref2);
  k_compact1<<<NB, 256, 0, stream>>>(f2, NN, bpref2, list2);

  const int gG = (2 * B + 31) / 32;
  const int gS = (NN + 31) / 32;

  // layer 1: X0 = A * bf16(emb), ALL rows (no frontier)
  k_spmm_all<<<gS, 256, 0, stream>>>(row_ptr_u, uslot, row_ptr_i, islot, Xe, X0, NN, NU);
  // layer 2: X1 = A * X0, f2 rows only
  k_spmm<<<gS, 256, 0, stream>>>(row_ptr_u, uslot, row_ptr_i, islot, X0, X1,
                                 list2, bpref2 + NB, NU);
  // tail: out = ((emb + X0) + X1 + A*X1)/4 + target masks, single write pass
  k_tail<<<gG, 256, 0, stream>>>(row_ptr_u, uslot, row_ptr_i, islot, X0, X1,
                                 uemb, iemb, users, items, out, B, NU,
                                 ku0, ku1, ki0, ki1);
}